// Round 1
// baseline (1196.631 us; speedup 1.0000x reference)
//
#include <hip/hip_runtime.h>
#include <hip/hip_bf16.h>
#include <math.h>

#define N_DRUG 50000
#define N_DIS  20000
#define NE     250000

typedef __bf16 bf16x8 __attribute__((ext_vector_type(8)));
typedef __bf16 bf16x4 __attribute__((ext_vector_type(4)));
typedef float  f32x4  __attribute__((ext_vector_type(4)));

__device__ __forceinline__ float gelu_exact(float x) {
  return 0.5f * x * (1.0f + erff(x * 0.7071067811865476f));
}

// ---------------------------------------------------------------------------
// Unified [M,128] @ [128,128] GEMM, bf16 MFMA (16x16x32), fp32 accumulate.
// MODE 0: outF = A_f32 @ W + bias                       (node transforms)
// MODE 1: outF = (num/(den+1e-16)) @ W + bias           (output linears)
// MODE 2: outB = sigmoid( gelu(ea@Wg1+bg1) @ W + bias ) (edge gate, bf16 out)
// ---------------------------------------------------------------------------
template <int MODE>
__global__ __launch_bounds__(256)
void gemm128(const float* __restrict__ A,
             const float* __restrict__ den,
             const float* __restrict__ W,
             const float* __restrict__ Wg1,
             const float* __restrict__ bg1,
             const float* __restrict__ bias,
             float* __restrict__ outF,
             __bf16* __restrict__ outB,
             int M, int ntiles)
{
  // +8 bf16 pad on rows: 2-way LDS bank aliasing only (free per m136)
  __shared__ __bf16 Alds[64][136];
  __shared__ __bf16 Wt[128][136];   // W transposed: Wt[n][k]

  const int tid = threadIdx.x;

  // stage W (once per block), transposed, bf16
  for (int idx = tid; idx < 16384; idx += 256) {
    int k = idx >> 7, n = idx & 127;
    Wt[n][k] = (__bf16)W[idx];
  }

  const int wv   = tid >> 6;
  const int lane = tid & 63;
  const int m16  = lane & 15;
  const int quad = lane >> 4;
  const f32x4 zero = {0.f, 0.f, 0.f, 0.f};

  for (int t = blockIdx.x; t < ntiles; t += gridDim.x) {
    const int r0 = t << 6;
    __syncthreads();   // covers W-staging (iter 0) and Alds reuse (iters > 0)

    // ---- stage A tile (64 rows x 128 cols) into LDS as bf16 ----
    if (MODE == 2) {
      for (int i = tid; i < 2048; i += 256) {
        int row = i >> 5, c4 = i & 31;
        int gr = r0 + row;
        f32x4 acc;
        #pragma unroll
        for (int j = 0; j < 4; ++j) acc[j] = bg1[c4 * 4 + j];
        if (gr < M) {
          const f32x4* ea4 = (const f32x4*)(A + (long)gr * 8);
          f32x4 e0 = ea4[0], e1 = ea4[1];
          #pragma unroll
          for (int k = 0; k < 4; ++k) {
            f32x4 w = ((const f32x4*)Wg1)[k * 32 + c4];
            #pragma unroll
            for (int j = 0; j < 4; ++j) acc[j] += e0[k] * w[j];
          }
          #pragma unroll
          for (int k = 0; k < 4; ++k) {
            f32x4 w = ((const f32x4*)Wg1)[(k + 4) * 32 + c4];
            #pragma unroll
            for (int j = 0; j < 4; ++j) acc[j] += e1[k] * w[j];
          }
        }
        bf16x4 b;
        #pragma unroll
        for (int j = 0; j < 4; ++j) b[j] = (__bf16)gelu_exact(acc[j]);
        *(bf16x4*)&Alds[row][c4 * 4] = b;
      }
    } else {
      for (int i = tid; i < 2048; i += 256) {
        int row = i >> 5, c4 = i & 31;
        int gr = r0 + row;
        f32x4 v = zero;
        if (gr < M) {
          v = ((const f32x4*)A)[(long)gr * 32 + c4];
          if (MODE == 1) {
            float r = 1.0f / (den[(long)gr * 4 + (c4 >> 3)] + 1e-16f);
            #pragma unroll
            for (int j = 0; j < 4; ++j) v[j] *= r;
          }
        }
        bf16x4 b;
        #pragma unroll
        for (int j = 0; j < 4; ++j) b[j] = (__bf16)v[j];
        *(bf16x4*)&Alds[row][c4 * 4] = b;
      }
    }
    __syncthreads();

    // ---- MFMA: wave wv computes tile rows [wv*16, wv*16+16) x all 128 cols
    f32x4 acc[8];
    #pragma unroll
    for (int ct = 0; ct < 8; ++ct) acc[ct] = zero;
    const int arow = wv * 16 + m16;
    #pragma unroll
    for (int kt = 0; kt < 4; ++kt) {
      bf16x8 a = *(const bf16x8*)&Alds[arow][kt * 32 + quad * 8];
      #pragma unroll
      for (int ct = 0; ct < 8; ++ct) {
        bf16x8 b = *(const bf16x8*)&Wt[ct * 16 + m16][kt * 32 + quad * 8];
        acc[ct] = __builtin_amdgcn_mfma_f32_16x16x32_bf16(a, b, acc[ct], 0, 0, 0);
      }
    }

    // ---- epilogue: C/D layout col=lane&15, row=quad*4+reg ----
    const int rb = r0 + wv * 16 + quad * 4;
    #pragma unroll
    for (int ct = 0; ct < 8; ++ct) {
      int col = ct * 16 + m16;
      float bv = bias[col];
      #pragma unroll
      for (int rg = 0; rg < 4; ++rg) {
        int gr = rb + rg;
        if (gr < M) {
          float v = acc[ct][rg] + bv;
          if (MODE == 2) {
            v = 1.0f / (1.0f + expf(-v));
            outB[(long)gr * 128 + col] = (__bf16)v;
          } else {
            outF[(long)gr * 128 + col] = v;
          }
        }
      }
    }
  }
}

// ---------------------------------------------------------------------------
// Edge conv: 32 lanes per edge (lane sub owns channels 4*sub..4*sub+3).
// logit_h = (Xs[s]·Xd[d])_h / sqrt(32) + (msg·attn)_h ; msg = (Xs[s]+Xd[d])*gate
// num[d,:] += msg*exp(logit), den[d,h] += exp(logit)  (fp32 atomics, no max
// subtraction: logits are O(±8), exp is safe in fp32 and result identical)
// ---------------------------------------------------------------------------
__global__ __launch_bounds__(256)
void edge_conv(const float* __restrict__ Xs,
               const float* __restrict__ Xd,
               const int* __restrict__ si,
               const int* __restrict__ di,
               const __bf16* __restrict__ gate,   // null for reverse conv
               const float* __restrict__ attn,
               float* __restrict__ num,
               float* __restrict__ den,
               int E, int hasGate)
{
  long gid = (long)blockIdx.x * 256 + threadIdx.x;
  int e = (int)(gid >> 5);
  if (e >= E) return;
  const int sub = threadIdx.x & 31;

  f32x4 at = ((const f32x4*)attn)[sub];
  int s = si[e], d = di[e];
  f32x4 xs = ((const f32x4*)(Xs + (long)s * 128))[sub];
  f32x4 xd = ((const f32x4*)(Xd + (long)d * 128))[sub];

  f32x4 msg;
  if (hasGate) {
    bf16x4 g = *(const bf16x4*)(gate + (long)e * 128 + sub * 4);
    #pragma unroll
    for (int j = 0; j < 4; ++j) msg[j] = (xs[j] + xd[j]) * (float)g[j];
  } else {
    #pragma unroll
    for (int j = 0; j < 4; ++j) msg[j] = xs[j] + xd[j];
  }

  float part = 0.f;
  #pragma unroll
  for (int j = 0; j < 4; ++j)
    part += xs[j] * xd[j] * 0.17677669529663687f + msg[j] * at[j];
  // reduce over the 8 lanes of this head (masks 1,2,4 stay inside the group)
  part += __shfl_xor(part, 1);
  part += __shfl_xor(part, 2);
  part += __shfl_xor(part, 4);
  float ex = expf(part);

  if ((sub & 7) == 0) atomicAdd(&den[(long)d * 4 + (sub >> 3)], ex);
  float* np = num + (long)d * 128 + sub * 4;
  atomicAdd(np + 0, msg[0] * ex);
  atomicAdd(np + 1, msg[1] * ex);
  atomicAdd(np + 2, msg[2] * ex);
  atomicAdd(np + 3, msg[3] * ex);
}

// ---------------------------------------------------------------------------
extern "C" void kernel_launch(void* const* d_in, const int* in_sizes, int n_in,
                              void* d_out, int out_size, void* d_ws, size_t ws_size,
                              hipStream_t stream)
{
  const float* x_drug  = (const float*)d_in[0];
  const float* x_dis   = (const float*)d_in[1];
  const float* ea      = (const float*)d_in[2];
  const int*   si_t    = (const int*)d_in[3];
  const int*   di_t    = (const int*)d_in[4];
  const int*   si_r    = (const int*)d_in[5];
  const int*   di_r    = (const int*)d_in[6];
  const float* Ws_t    = (const float*)d_in[7];
  const float* bs_t    = (const float*)d_in[8];
  const float* Wd_t    = (const float*)d_in[9];
  const float* bd_t    = (const float*)d_in[10];
  const float* attn_t  = (const float*)d_in[11];
  const float* Wg1     = (const float*)d_in[12];
  const float* bg1     = (const float*)d_in[13];
  const float* Wg2     = (const float*)d_in[14];
  const float* bg2     = (const float*)d_in[15];
  const float* Ws_r    = (const float*)d_in[16];
  const float* bs_r    = (const float*)d_in[17];
  const float* Wd_r    = (const float*)d_in[18];
  const float* bd_r    = (const float*)d_in[19];
  const float* attn_r  = (const float*)d_in[20];
  const float* Wo_drug = (const float*)d_in[21];
  const float* bo_drug = (const float*)d_in[22];
  const float* Wo_dis  = (const float*)d_in[23];
  const float* bo_dis  = (const float*)d_in[24];

  // workspace layout (fp32 counts); total ~173 MB
  float* ws       = (float*)d_ws;
  float* Xs_t     = ws;                    // 50000*128
  float* Xd_t     = Xs_t + 6400000;        // 20000*128
  float* Xs_r     = Xd_t + 2560000;        // 20000*128
  float* Xd_r     = Xs_r + 2560000;        // 50000*128
  float* num_drug = Xd_r + 6400000;        // 50000*128  --+
  float* num_dis  = num_drug + 6400000;    // 20000*128    | zeroed as one
  float* den_drug = num_dis + 2560000;     // 50000*4      | contiguous region
  float* den_dis  = den_drug + 200000;     // 20000*4    --+
  __bf16* gate    = (__bf16*)(den_dis + 80000);  // 250000*128 bf16

  float* out_drug = (float*)d_out;
  float* out_dis  = out_drug + (long)N_DRUG * 128;

  hipMemsetAsync(num_drug, 0, (size_t)9240000 * sizeof(float), stream);

  const int nt_drug = (N_DRUG + 63) / 64;  // 782
  const int nt_dis  = (N_DIS + 63) / 64;   // 313
  const int nt_e    = (NE + 63) / 64;      // 3907
  auto grid = [](int nt) { return nt < 768 ? nt : 768; };

  // node transforms: X = x @ W + b  (gather moved after the linear)
  gemm128<0><<<grid(nt_drug), 256, 0, stream>>>(x_drug, nullptr, Ws_t, nullptr, nullptr, bs_t, Xs_t, nullptr, N_DRUG, nt_drug);
  gemm128<0><<<grid(nt_dis),  256, 0, stream>>>(x_dis,  nullptr, Wd_t, nullptr, nullptr, bd_t, Xd_t, nullptr, N_DIS,  nt_dis);
  gemm128<0><<<grid(nt_dis),  256, 0, stream>>>(x_dis,  nullptr, Ws_r, nullptr, nullptr, bs_r, Xs_r, nullptr, N_DIS,  nt_dis);
  gemm128<0><<<grid(nt_drug), 256, 0, stream>>>(x_drug, nullptr, Wd_r, nullptr, nullptr, bd_r, Xd_r, nullptr, N_DRUG, nt_drug);

  // edge gate: sigmoid(gelu(ea@Wg1+bg1)@Wg2+bg2), hidden fused into staging
  gemm128<2><<<grid(nt_e), 256, 0, stream>>>(ea, nullptr, Wg2, Wg1, bg1, bg2, nullptr, gate, NE, nt_e);

  // edge convs (atomic aggregation)
  edge_conv<<<NE / 8, 256, 0, stream>>>(Xs_t, Xd_t, si_t, di_t, gate,    attn_t, num_dis,  den_dis,  NE, 1);
  edge_conv<<<NE / 8, 256, 0, stream>>>(Xs_r, Xd_r, si_r, di_r, nullptr, attn_r, num_drug, den_drug, NE, 0);

  // output linears with fused softmax normalization
  gemm128<1><<<grid(nt_drug), 256, 0, stream>>>(num_drug, den_drug, Wo_drug, nullptr, nullptr, bo_drug, out_drug, nullptr, N_DRUG, nt_drug);
  gemm128<1><<<grid(nt_dis),  256, 0, stream>>>(num_dis,  den_dis,  Wo_dis,  nullptr, nullptr, bo_dis,  out_dis,  nullptr, N_DIS,  nt_dis);
}

// Round 2
// 603.743 us; speedup vs baseline: 1.9820x; 1.9820x over previous
//
#include <hip/hip_runtime.h>
#include <hip/hip_bf16.h>
#include <math.h>

#define N_DRUG 50000
#define N_DIS  20000
#define NE     250000

typedef __bf16 bf16x8 __attribute__((ext_vector_type(8)));
typedef __bf16 bf16x4 __attribute__((ext_vector_type(4)));
typedef __bf16 bf16x2 __attribute__((ext_vector_type(2)));
typedef float  f32x4  __attribute__((ext_vector_type(4)));
typedef float  f32x2  __attribute__((ext_vector_type(2)));

__device__ __forceinline__ float gelu_exact(float x) {
  return 0.5f * x * (1.0f + erff(x * 0.7071067811865476f));
}

// ---------------------------------------------------------------------------
// Unified [M,128] @ [128,128] GEMM, bf16 MFMA (16x16x32), fp32 accumulate.
// MODE 0: outF = A_f32 @ W + bias                       (node/output linears)
// MODE 2: outB = sigmoid( gelu(ea@Wg1+bg1) @ W + bias ) (edge gate, bf16 out)
// ---------------------------------------------------------------------------
template <int MODE>
__global__ __launch_bounds__(256)
void gemm128(const float* __restrict__ A,
             const float* __restrict__ W,
             const float* __restrict__ Wg1,
             const float* __restrict__ bg1,
             const float* __restrict__ bias,
             float* __restrict__ outF,
             __bf16* __restrict__ outB,
             int M, int ntiles)
{
  __shared__ __bf16 Alds[64][136];
  __shared__ __bf16 Wt[128][136];   // W transposed: Wt[n][k]

  const int tid = threadIdx.x;

  for (int idx = tid; idx < 16384; idx += 256) {
    int k = idx >> 7, n = idx & 127;
    Wt[n][k] = (__bf16)W[idx];
  }

  const int wv   = tid >> 6;
  const int lane = tid & 63;
  const int m16  = lane & 15;
  const int quad = lane >> 4;
  const f32x4 zero = {0.f, 0.f, 0.f, 0.f};

  for (int t = blockIdx.x; t < ntiles; t += gridDim.x) {
    const int r0 = t << 6;
    __syncthreads();   // covers W-staging (iter 0) and Alds reuse (iters > 0)

    if (MODE == 2) {
      for (int i = tid; i < 2048; i += 256) {
        int row = i >> 5, c4 = i & 31;
        int gr = r0 + row;
        f32x4 acc;
        #pragma unroll
        for (int j = 0; j < 4; ++j) acc[j] = bg1[c4 * 4 + j];
        if (gr < M) {
          const f32x4* ea4 = (const f32x4*)(A + (long)gr * 8);
          f32x4 e0 = ea4[0], e1 = ea4[1];
          #pragma unroll
          for (int k = 0; k < 4; ++k) {
            f32x4 w = ((const f32x4*)Wg1)[k * 32 + c4];
            #pragma unroll
            for (int j = 0; j < 4; ++j) acc[j] += e0[k] * w[j];
          }
          #pragma unroll
          for (int k = 0; k < 4; ++k) {
            f32x4 w = ((const f32x4*)Wg1)[(k + 4) * 32 + c4];
            #pragma unroll
            for (int j = 0; j < 4; ++j) acc[j] += e1[k] * w[j];
          }
        }
        bf16x4 b;
        #pragma unroll
        for (int j = 0; j < 4; ++j) b[j] = (__bf16)gelu_exact(acc[j]);
        *(bf16x4*)&Alds[row][c4 * 4] = b;
      }
    } else {
      for (int i = tid; i < 2048; i += 256) {
        int row = i >> 5, c4 = i & 31;
        int gr = r0 + row;
        f32x4 v = zero;
        if (gr < M) v = ((const f32x4*)A)[(long)gr * 32 + c4];
        bf16x4 b;
        #pragma unroll
        for (int j = 0; j < 4; ++j) b[j] = (__bf16)v[j];
        *(bf16x4*)&Alds[row][c4 * 4] = b;
      }
    }
    __syncthreads();

    f32x4 acc[8];
    #pragma unroll
    for (int ct = 0; ct < 8; ++ct) acc[ct] = zero;
    const int arow = wv * 16 + m16;
    #pragma unroll
    for (int kt = 0; kt < 4; ++kt) {
      bf16x8 a = *(const bf16x8*)&Alds[arow][kt * 32 + quad * 8];
      #pragma unroll
      for (int ct = 0; ct < 8; ++ct) {
        bf16x8 b = *(const bf16x8*)&Wt[ct * 16 + m16][kt * 32 + quad * 8];
        acc[ct] = __builtin_amdgcn_mfma_f32_16x16x32_bf16(a, b, acc[ct], 0, 0, 0);
      }
    }

    // C/D layout: col=lane&15, row=quad*4+reg
    const int rb = r0 + wv * 16 + quad * 4;
    #pragma unroll
    for (int ct = 0; ct < 8; ++ct) {
      int col = ct * 16 + m16;
      float bv = bias[col];
      #pragma unroll
      for (int rg = 0; rg < 4; ++rg) {
        int gr = rb + rg;
        if (gr < M) {
          float v = acc[ct][rg] + bv;
          if (MODE == 2) {
            v = 1.0f / (1.0f + expf(-v));
            outB[(long)gr * 128 + col] = (__bf16)v;
          } else {
            outF[(long)gr * 128 + col] = v;
          }
        }
      }
    }
  }
}

// ---------------------------------------------------------------------------
// Counting sort of edges by destination node
// ---------------------------------------------------------------------------
__global__ __launch_bounds__(256)
void histo(const int* __restrict__ di, int* __restrict__ cnt, int E) {
  int i = blockIdx.x * 256 + threadIdx.x;
  if (i < E) atomicAdd(&cnt[di[i]], 1);
}

__global__ __launch_bounds__(1024)
void exscan(const int* __restrict__ cnt, int* __restrict__ offs,
            int* __restrict__ cursor, int n) {
  __shared__ int part[1024];
  int tid = threadIdx.x;
  int chunk = (n + 1023) / 1024;
  int lo = tid * chunk;
  int hi = lo + chunk; if (hi > n) hi = n;
  int s = 0;
  for (int i = lo; i < hi; ++i) s += cnt[i];
  part[tid] = s;
  __syncthreads();
  for (int d = 1; d < 1024; d <<= 1) {
    int v = (tid >= d) ? part[tid - d] : 0;
    __syncthreads();
    part[tid] += v;
    __syncthreads();
  }
  int run = (tid ? part[tid - 1] : 0);
  for (int i = lo; i < hi; ++i) {
    offs[i] = run; cursor[i] = run;
    run += cnt[i];
  }
}

__global__ __launch_bounds__(256)
void scatter(const int* __restrict__ di, int* __restrict__ cursor,
             int* __restrict__ sorted, int E) {
  int i = blockIdx.x * 256 + threadIdx.x;
  if (i < E) {
    int p = atomicAdd(&cursor[di[i]], 1);
    sorted[p] = i;
  }
}

// ---------------------------------------------------------------------------
// Gather-side aggregation: one 64-lane wave per destination node; lane owns
// channels {2*lane, 2*lane+1}. Head h = lane/16; logit reduction via
// shfl_xor 1,2,4,8 within the 16-lane head group. Softmax normalization
// fused in the epilogue (no max-subtraction: logits are O(±8), exp is safe
// in fp32, result identical after the division).
// ---------------------------------------------------------------------------
template <int HASGATE>
__global__ __launch_bounds__(256)
void aggregate(const float* __restrict__ Xs, const float* __restrict__ Xd,
               const int* __restrict__ si, const int* __restrict__ sorted,
               const int* __restrict__ offs, const int* __restrict__ cnt,
               const __bf16* __restrict__ gate, const float* __restrict__ attn,
               float* __restrict__ out, int n)
{
  int w = (int)((blockIdx.x * 256 + threadIdx.x) >> 6);
  if (w >= n) return;
  const int lane = threadIdx.x & 63;
  const int c = lane * 2;

  f32x2 at = *(const f32x2*)(attn + c);
  f32x2 xd = *(const f32x2*)(Xd + (long)w * 128 + c);
  const int start = offs[w];
  const int m = cnt[w];

  float n0 = 0.f, n1 = 0.f, den = 0.f;

  // software-pipeline the index chain (sorted -> si) one edge ahead
  int e = 0, s = 0;
  if (m > 0) { e = sorted[start]; s = si[e]; }
  for (int j = 0; j < m; ++j) {
    int e_cur = e, s_cur = s;
    if (j + 1 < m) { e = sorted[start + j + 1]; s = si[e]; }

    f32x2 xs = *(const f32x2*)(Xs + (long)s_cur * 128 + c);
    float m0 = xs[0] + xd[0], m1 = xs[1] + xd[1];
    if (HASGATE) {
      bf16x2 g = *(const bf16x2*)(gate + (long)e_cur * 128 + c);
      m0 *= (float)g[0];
      m1 *= (float)g[1];
    }
    float part = (xs[0] * xd[0] + xs[1] * xd[1]) * 0.17677669529663687f
               + m0 * at[0] + m1 * at[1];
    part += __shfl_xor(part, 1);
    part += __shfl_xor(part, 2);
    part += __shfl_xor(part, 4);
    part += __shfl_xor(part, 8);
    float ex = expf(part);
    n0 += m0 * ex;
    n1 += m1 * ex;
    den += ex;
  }

  float r = 1.0f / (den + 1e-16f);
  f32x2 o = {n0 * r, n1 * r};
  *(f32x2*)(out + (long)w * 128 + c) = o;
}

// ---------------------------------------------------------------------------
extern "C" void kernel_launch(void* const* d_in, const int* in_sizes, int n_in,
                              void* d_out, int out_size, void* d_ws, size_t ws_size,
                              hipStream_t stream)
{
  const float* x_drug  = (const float*)d_in[0];
  const float* x_dis   = (const float*)d_in[1];
  const float* ea      = (const float*)d_in[2];
  const int*   si_t    = (const int*)d_in[3];
  const int*   di_t    = (const int*)d_in[4];
  const int*   si_r    = (const int*)d_in[5];
  const int*   di_r    = (const int*)d_in[6];
  const float* Ws_t    = (const float*)d_in[7];
  const float* bs_t    = (const float*)d_in[8];
  const float* Wd_t    = (const float*)d_in[9];
  const float* bd_t    = (const float*)d_in[10];
  const float* attn_t  = (const float*)d_in[11];
  const float* Wg1     = (const float*)d_in[12];
  const float* bg1     = (const float*)d_in[13];
  const float* Wg2     = (const float*)d_in[14];
  const float* bg2     = (const float*)d_in[15];
  const float* Ws_r    = (const float*)d_in[16];
  const float* bs_r    = (const float*)d_in[17];
  const float* Wd_r    = (const float*)d_in[18];
  const float* bd_r    = (const float*)d_in[19];
  const float* attn_r  = (const float*)d_in[20];
  const float* Wo_drug = (const float*)d_in[21];
  const float* bo_drug = (const float*)d_in[22];
  const float* Wo_dis  = (const float*)d_in[23];
  const float* bo_dis  = (const float*)d_in[24];

  // workspace layout (~117 MB)
  float* ws       = (float*)d_ws;
  float* Xs_t     = ws;                    // 50000*128 f32 (reused as aggr_drug)
  float* Xd_t     = Xs_t + 6400000;        // 20000*128 f32
  float* Xs_r     = Xd_t + 2560000;        // 20000*128 f32
  float* Xd_r     = Xs_r + 2560000;        // 50000*128 f32
  float* aggr_dis = Xd_r + 6400000;        // 20000*128 f32
  __bf16* gate    = (__bf16*)(aggr_dis + 2560000);  // 250000*128 bf16
  int* cnt_dis    = (int*)(gate + (long)NE * 128);  // 20000  --+ zeroed as one
  int* cnt_drug   = cnt_dis + 20000;       // 50000             --+
  int* offs_dis   = cnt_drug + 50000;      // 20000
  int* offs_drug  = offs_dis + 20000;      // 50000
  int* cur_dis    = offs_drug + 50000;     // 20000
  int* cur_drug   = cur_dis + 20000;       // 50000
  int* sorted_t   = cur_drug + 50000;      // 250000
  int* sorted_r   = sorted_t + 250000;     // 250000

  float* aggr_drug = Xs_t;                 // safe: Xs_t dead after treats agg

  float* out_drug = (float*)d_out;
  float* out_dis  = out_drug + (long)N_DRUG * 128;

  hipMemsetAsync(cnt_dis, 0, 70000 * sizeof(int), stream);

  const int nt_drug = (N_DRUG + 63) / 64;  // 782
  const int nt_dis  = (N_DIS + 63) / 64;   // 313
  const int nt_e    = (NE + 63) / 64;      // 3907
  auto grid = [](int nt) { return nt < 768 ? nt : 768; };
  const int eb = (NE + 255) / 256;         // 977

  // node transforms: X = x @ W + b  (gather moved after the linear)
  gemm128<0><<<grid(nt_drug), 256, 0, stream>>>(x_drug, Ws_t, nullptr, nullptr, bs_t, Xs_t, nullptr, N_DRUG, nt_drug);
  gemm128<0><<<grid(nt_dis),  256, 0, stream>>>(x_dis,  Wd_t, nullptr, nullptr, bd_t, Xd_t, nullptr, N_DIS,  nt_dis);
  gemm128<0><<<grid(nt_dis),  256, 0, stream>>>(x_dis,  Ws_r, nullptr, nullptr, bs_r, Xs_r, nullptr, N_DIS,  nt_dis);
  gemm128<0><<<grid(nt_drug), 256, 0, stream>>>(x_drug, Wd_r, nullptr, nullptr, bd_r, Xd_r, nullptr, N_DRUG, nt_drug);

  // edge gate: sigmoid(gelu(ea@Wg1+bg1)@Wg2+bg2), hidden fused into staging
  gemm128<2><<<grid(nt_e), 256, 0, stream>>>(ea, Wg2, Wg1, bg1, bg2, nullptr, gate, NE, nt_e);

  // counting sort by destination (both convs)
  histo<<<eb, 256, 0, stream>>>(di_t, cnt_dis,  NE);
  histo<<<eb, 256, 0, stream>>>(di_r, cnt_drug, NE);
  exscan<<<1, 1024, 0, stream>>>(cnt_dis,  offs_dis,  cur_dis,  N_DIS);
  exscan<<<1, 1024, 0, stream>>>(cnt_drug, offs_drug, cur_drug, N_DRUG);
  scatter<<<eb, 256, 0, stream>>>(di_t, cur_dis,  sorted_t, NE);
  scatter<<<eb, 256, 0, stream>>>(di_r, cur_drug, sorted_r, NE);

  // gather-side aggregation, one wave per destination node (no atomics)
  aggregate<1><<<(N_DIS + 3) / 4,  256, 0, stream>>>(Xs_t, Xd_t, si_t, sorted_t, offs_dis,  cnt_dis,  gate,    attn_t, aggr_dis,  N_DIS);
  aggregate<0><<<(N_DRUG + 3) / 4, 256, 0, stream>>>(Xs_r, Xd_r, si_r, sorted_r, offs_drug, cnt_drug, nullptr, attn_r, aggr_drug, N_DRUG);

  // output linears (softmax normalization already fused into aggregation)
  gemm128<0><<<grid(nt_drug), 256, 0, stream>>>(aggr_drug, Wo_drug, nullptr, nullptr, bo_drug, out_drug, nullptr, N_DRUG, nt_drug);
  gemm128<0><<<grid(nt_dis),  256, 0, stream>>>(aggr_dis,  Wo_dis,  nullptr, nullptr, bo_dis,  out_dis,  nullptr, N_DIS,  nt_dis);
}

// Round 3
// 460.441 us; speedup vs baseline: 2.5989x; 1.3112x over previous
//
#include <hip/hip_runtime.h>
#include <hip/hip_bf16.h>
#include <math.h>

#define N_DRUG 50000
#define N_DIS  20000
#define NE     250000

// scan geometry: segment 0 = cnt_dis (20000), segment 1 = cnt_drug (50000)
#define NB0 79     // ceil(20000/256)
#define NBT 275    // NB0 + ceil(50000/256)

typedef __bf16 bf16x8 __attribute__((ext_vector_type(8)));
typedef __bf16 bf16x4 __attribute__((ext_vector_type(4)));
typedef __bf16 bf16x2 __attribute__((ext_vector_type(2)));
typedef float  f32x4  __attribute__((ext_vector_type(4)));
typedef float  f32x2  __attribute__((ext_vector_type(2)));

__device__ __forceinline__ float gelu_exact(float x) {
  return 0.5f * x * (1.0f + erff(x * 0.7071067811865476f));
}

// ---------------------------------------------------------------------------
// Unified [M,128] @ [128,128] GEMM, bf16 MFMA (16x16x32), fp32 accumulate.
// MODE 0: outF = A_f32 @ W + bias                       (node/output linears)
// MODE 2: outB = sigmoid( gelu(ea@Wg1+bg1) @ W + bias ) (edge gate, bf16 out)
// ---------------------------------------------------------------------------
template <int MODE>
__global__ __launch_bounds__(256)
void gemm128(const float* __restrict__ A,
             const float* __restrict__ W,
             const float* __restrict__ Wg1,
             const float* __restrict__ bg1,
             const float* __restrict__ bias,
             float* __restrict__ outF,
             __bf16* __restrict__ outB,
             int M, int ntiles)
{
  __shared__ __bf16 Alds[64][136];
  __shared__ __bf16 Wt[128][136];   // W transposed: Wt[n][k]

  const int tid = threadIdx.x;

  for (int idx = tid; idx < 16384; idx += 256) {
    int k = idx >> 7, n = idx & 127;
    Wt[n][k] = (__bf16)W[idx];
  }

  const int wv   = tid >> 6;
  const int lane = tid & 63;
  const int m16  = lane & 15;
  const int quad = lane >> 4;
  const f32x4 zero = {0.f, 0.f, 0.f, 0.f};

  for (int t = blockIdx.x; t < ntiles; t += gridDim.x) {
    const int r0 = t << 6;
    __syncthreads();   // covers W-staging (iter 0) and Alds reuse (iters > 0)

    if (MODE == 2) {
      for (int i = tid; i < 2048; i += 256) {
        int row = i >> 5, c4 = i & 31;
        int gr = r0 + row;
        f32x4 acc;
        #pragma unroll
        for (int j = 0; j < 4; ++j) acc[j] = bg1[c4 * 4 + j];
        if (gr < M) {
          const f32x4* ea4 = (const f32x4*)(A + (long)gr * 8);
          f32x4 e0 = ea4[0], e1 = ea4[1];
          #pragma unroll
          for (int k = 0; k < 4; ++k) {
            f32x4 w = ((const f32x4*)Wg1)[k * 32 + c4];
            #pragma unroll
            for (int j = 0; j < 4; ++j) acc[j] += e0[k] * w[j];
          }
          #pragma unroll
          for (int k = 0; k < 4; ++k) {
            f32x4 w = ((const f32x4*)Wg1)[(k + 4) * 32 + c4];
            #pragma unroll
            for (int j = 0; j < 4; ++j) acc[j] += e1[k] * w[j];
          }
        }
        bf16x4 b;
        #pragma unroll
        for (int j = 0; j < 4; ++j) b[j] = (__bf16)gelu_exact(acc[j]);
        *(bf16x4*)&Alds[row][c4 * 4] = b;
      }
    } else {
      for (int i = tid; i < 2048; i += 256) {
        int row = i >> 5, c4 = i & 31;
        int gr = r0 + row;
        f32x4 v = zero;
        if (gr < M) v = ((const f32x4*)A)[(long)gr * 32 + c4];
        bf16x4 b;
        #pragma unroll
        for (int j = 0; j < 4; ++j) b[j] = (__bf16)v[j];
        *(bf16x4*)&Alds[row][c4 * 4] = b;
      }
    }
    __syncthreads();

    f32x4 acc[8];
    #pragma unroll
    for (int ct = 0; ct < 8; ++ct) acc[ct] = zero;
    const int arow = wv * 16 + m16;
    #pragma unroll
    for (int kt = 0; kt < 4; ++kt) {
      bf16x8 a = *(const bf16x8*)&Alds[arow][kt * 32 + quad * 8];
      #pragma unroll
      for (int ct = 0; ct < 8; ++ct) {
        bf16x8 b = *(const bf16x8*)&Wt[ct * 16 + m16][kt * 32 + quad * 8];
        acc[ct] = __builtin_amdgcn_mfma_f32_16x16x32_bf16(a, b, acc[ct], 0, 0, 0);
      }
    }

    // C/D layout: col=lane&15, row=quad*4+reg
    const int rb = r0 + wv * 16 + quad * 4;
    #pragma unroll
    for (int ct = 0; ct < 8; ++ct) {
      int col = ct * 16 + m16;
      float bv = bias[col];
      #pragma unroll
      for (int rg = 0; rg < 4; ++rg) {
        int gr = rb + rg;
        if (gr < M) {
          float v = acc[ct][rg] + bv;
          if (MODE == 2) {
            v = 1.0f / (1.0f + expf(-v));
            outB[(long)gr * 128 + col] = (__bf16)v;
          } else {
            outF[(long)gr * 128 + col] = v;
          }
        }
      }
    }
  }
}

// ---------------------------------------------------------------------------
// Counting sort of edges by destination node.
// histo2/scatter2 handle both edge types in one launch (blockIdx split).
// ---------------------------------------------------------------------------
__global__ __launch_bounds__(256)
void histo2(const int* __restrict__ di_t, const int* __restrict__ di_r,
            int* __restrict__ cnt_dis, int* __restrict__ cnt_drug, int half) {
  int b = blockIdx.x;
  if (b < half) {
    int i = b * 256 + threadIdx.x;
    if (i < NE) atomicAdd(&cnt_dis[di_t[i]], 1);
  } else {
    int i = (b - half) * 256 + threadIdx.x;
    if (i < NE) atomicAdd(&cnt_drug[di_r[i]], 1);
  }
}

__global__ __launch_bounds__(256)
void scatter2(const int* __restrict__ di_t, const int* __restrict__ di_r,
              int* __restrict__ cur_dis, int* __restrict__ cur_drug,
              int* __restrict__ sorted_t, int* __restrict__ sorted_r, int half) {
  int b = blockIdx.x;
  if (b < half) {
    int i = b * 256 + threadIdx.x;
    if (i < NE) sorted_t[atomicAdd(&cur_dis[di_t[i]], 1)] = i;
  } else {
    int i = (b - half) * 256 + threadIdx.x;
    if (i < NE) sorted_r[atomicAdd(&cur_drug[di_r[i]], 1)] = i;
  }
}

// ---------------------------------------------------------------------------
// Device-wide segmented exclusive scan over concatenated cnt_dis||cnt_drug.
// Phase 1: per-block sums. Phase 2: segmented scan of 275 block sums
// (single small block — trivial). Phase 3: local rescan + block base.
// ---------------------------------------------------------------------------
__device__ __forceinline__ void seg_geom(int b, int& base, int& n, int& lb) {
  if (b < NB0) { base = 0;     n = 20000; lb = b; }
  else         { base = 20000; n = 50000; lb = b - NB0; }
}

__global__ __launch_bounds__(256)
void scan_partial(const int* __restrict__ cnt, int* __restrict__ bsum) {
  __shared__ int sh[256];
  int b = blockIdx.x, t = threadIdx.x;
  int base, n, lb; seg_geom(b, base, n, lb);
  int i = lb * 256 + t;
  sh[t] = (i < n) ? cnt[base + i] : 0;
  __syncthreads();
  for (int d = 1; d < 256; d <<= 1) {
    int vv = (t >= d) ? sh[t - d] : 0;
    __syncthreads();
    sh[t] += vv;
    __syncthreads();
  }
  if (t == 255) bsum[b] = sh[255];
}

__global__ __launch_bounds__(512)
void scan_block(const int* __restrict__ bsum, int* __restrict__ bexc) {
  __shared__ int v[512];
  __shared__ int f[512];
  int t = threadIdx.x;
  int own = (t < NBT) ? bsum[t] : 0;
  v[t] = own;
  f[t] = (t == 0 || t == NB0 || t >= NBT) ? 1 : 0;
  __syncthreads();
  for (int d = 1; d < 512; d <<= 1) {
    int vv = 0, ff = 1;
    if (t >= d) { vv = v[t - d]; ff = f[t - d]; }
    __syncthreads();
    if (t >= d && !f[t]) { v[t] += vv; f[t] |= ff; }
    __syncthreads();
  }
  if (t < NBT) bexc[t] = v[t] - own;   // exclusive within segment
}

__global__ __launch_bounds__(256)
void scan_final(const int* __restrict__ cnt, const int* __restrict__ bexc,
                int* __restrict__ offs, int* __restrict__ cursor) {
  __shared__ int sh[256];
  int b = blockIdx.x, t = threadIdx.x;
  int base, n, lb; seg_geom(b, base, n, lb);
  int i = lb * 256 + t;
  int own = (i < n) ? cnt[base + i] : 0;
  sh[t] = own;
  __syncthreads();
  for (int d = 1; d < 256; d <<= 1) {
    int vv = (t >= d) ? sh[t - d] : 0;
    __syncthreads();
    sh[t] += vv;
    __syncthreads();
  }
  int off = bexc[b] + sh[t] - own;     // exclusive prefix + block base
  if (i < n) { offs[base + i] = off; cursor[base + i] = off; }
}

// ---------------------------------------------------------------------------
// Gather-side aggregation: one 64-lane wave per destination node; lane owns
// channels {2*lane, 2*lane+1}. Softmax normalization fused in the epilogue
// (no max-subtraction: logits are O(±8), exp safe in fp32, result identical).
// ---------------------------------------------------------------------------
template <int HASGATE>
__global__ __launch_bounds__(256)
void aggregate(const float* __restrict__ Xs, const float* __restrict__ Xd,
               const int* __restrict__ si, const int* __restrict__ sorted,
               const int* __restrict__ offs, const int* __restrict__ cnt,
               const __bf16* __restrict__ gate, const float* __restrict__ attn,
               float* __restrict__ out, int n)
{
  int w = (int)((blockIdx.x * 256 + threadIdx.x) >> 6);
  if (w >= n) return;
  const int lane = threadIdx.x & 63;
  const int c = lane * 2;

  f32x2 at = *(const f32x2*)(attn + c);
  f32x2 xd = *(const f32x2*)(Xd + (long)w * 128 + c);
  const int start = offs[w];
  const int m = cnt[w];

  float n0 = 0.f, n1 = 0.f, den = 0.f;

  // software-pipeline the index chain (sorted -> si) one edge ahead
  int e = 0, s = 0;
  if (m > 0) { e = sorted[start]; s = si[e]; }
  for (int j = 0; j < m; ++j) {
    int e_cur = e, s_cur = s;
    if (j + 1 < m) { e = sorted[start + j + 1]; s = si[e]; }

    f32x2 xs = *(const f32x2*)(Xs + (long)s_cur * 128 + c);
    float m0 = xs[0] + xd[0], m1 = xs[1] + xd[1];
    if (HASGATE) {
      bf16x2 g = *(const bf16x2*)(gate + (long)e_cur * 128 + c);
      m0 *= (float)g[0];
      m1 *= (float)g[1];
    }
    float part = (xs[0] * xd[0] + xs[1] * xd[1]) * 0.17677669529663687f
               + m0 * at[0] + m1 * at[1];
    part += __shfl_xor(part, 1);
    part += __shfl_xor(part, 2);
    part += __shfl_xor(part, 4);
    part += __shfl_xor(part, 8);
    float ex = expf(part);
    n0 += m0 * ex;
    n1 += m1 * ex;
    den += ex;
  }

  float r = 1.0f / (den + 1e-16f);
  f32x2 o = {n0 * r, n1 * r};
  *(f32x2*)(out + (long)w * 128 + c) = o;
}

// ---------------------------------------------------------------------------
extern "C" void kernel_launch(void* const* d_in, const int* in_sizes, int n_in,
                              void* d_out, int out_size, void* d_ws, size_t ws_size,
                              hipStream_t stream)
{
  const float* x_drug  = (const float*)d_in[0];
  const float* x_dis   = (const float*)d_in[1];
  const float* ea      = (const float*)d_in[2];
  const int*   si_t    = (const int*)d_in[3];
  const int*   di_t    = (const int*)d_in[4];
  const int*   si_r    = (const int*)d_in[5];
  const int*   di_r    = (const int*)d_in[6];
  const float* Ws_t    = (const float*)d_in[7];
  const float* bs_t    = (const float*)d_in[8];
  const float* Wd_t    = (const float*)d_in[9];
  const float* bd_t    = (const float*)d_in[10];
  const float* attn_t  = (const float*)d_in[11];
  const float* Wg1     = (const float*)d_in[12];
  const float* bg1     = (const float*)d_in[13];
  const float* Wg2     = (const float*)d_in[14];
  const float* bg2     = (const float*)d_in[15];
  const float* Ws_r    = (const float*)d_in[16];
  const float* bs_r    = (const float*)d_in[17];
  const float* Wd_r    = (const float*)d_in[18];
  const float* bd_r    = (const float*)d_in[19];
  const float* attn_r  = (const float*)d_in[20];
  const float* Wo_drug = (const float*)d_in[21];
  const float* bo_drug = (const float*)d_in[22];
  const float* Wo_dis  = (const float*)d_in[23];
  const float* bo_dis  = (const float*)d_in[24];

  // workspace layout (~117 MB)
  float* ws       = (float*)d_ws;
  float* Xs_t     = ws;                    // 50000*128 f32 (reused as aggr_drug)
  float* Xd_t     = Xs_t + 6400000;        // 20000*128 f32
  float* Xs_r     = Xd_t + 2560000;        // 20000*128 f32
  float* Xd_r     = Xs_r + 2560000;        // 50000*128 f32
  float* aggr_dis = Xd_r + 6400000;        // 20000*128 f32
  __bf16* gate    = (__bf16*)(aggr_dis + 2560000);  // 250000*128 bf16
  int* cnt_dis    = (int*)(gate + (long)NE * 128);  // 20000  --+ contiguous:
  int* cnt_drug   = cnt_dis + 20000;       // 50000             | zeroed + scanned
  int* offs_dis   = cnt_drug + 50000;      // 20000             | as one region
  int* offs_drug  = offs_dis + 20000;      // 50000             |
  int* cur_dis    = offs_drug + 50000;     // 20000             |
  int* cur_drug   = cur_dis + 20000;       // 50000           --+
  int* sorted_t   = cur_drug + 50000;      // 250000
  int* sorted_r   = sorted_t + 250000;     // 250000
  int* bsum       = sorted_r + 250000;     // 275
  int* bexc       = bsum + 512;            // 275

  float* aggr_drug = Xs_t;                 // safe: Xs_t dead after treats agg

  float* out_drug = (float*)d_out;
  float* out_dis  = out_drug + (long)N_DRUG * 128;

  hipMemsetAsync(cnt_dis, 0, 70000 * sizeof(int), stream);

  const int nt_drug = (N_DRUG + 63) / 64;  // 782
  const int nt_dis  = (N_DIS + 63) / 64;   // 313
  const int nt_e    = (NE + 63) / 64;      // 3907
  auto grid = [](int nt) { return nt < 768 ? nt : 768; };
  const int eb = (NE + 255) / 256;         // 977

  // node transforms: X = x @ W + b  (gather moved after the linear)
  gemm128<0><<<grid(nt_drug), 256, 0, stream>>>(x_drug, Ws_t, nullptr, nullptr, bs_t, Xs_t, nullptr, N_DRUG, nt_drug);
  gemm128<0><<<grid(nt_dis),  256, 0, stream>>>(x_dis,  Wd_t, nullptr, nullptr, bd_t, Xd_t, nullptr, N_DIS,  nt_dis);
  gemm128<0><<<grid(nt_dis),  256, 0, stream>>>(x_dis,  Ws_r, nullptr, nullptr, bs_r, Xs_r, nullptr, N_DIS,  nt_dis);
  gemm128<0><<<grid(nt_drug), 256, 0, stream>>>(x_drug, Wd_r, nullptr, nullptr, bd_r, Xd_r, nullptr, N_DRUG, nt_drug);

  // edge gate: sigmoid(gelu(ea@Wg1+bg1)@Wg2+bg2), hidden fused into staging
  gemm128<2><<<grid(nt_e), 256, 0, stream>>>(ea, Wg2, Wg1, bg1, bg2, nullptr, gate, NE, nt_e);

  // counting sort by destination (both convs), device-wide 3-phase scan
  histo2<<<2 * eb, 256, 0, stream>>>(di_t, di_r, cnt_dis, cnt_drug, eb);
  scan_partial<<<NBT, 256, 0, stream>>>(cnt_dis, bsum);
  scan_block<<<1, 512, 0, stream>>>(bsum, bexc);
  scan_final<<<NBT, 256, 0, stream>>>(cnt_dis, bexc, offs_dis, cur_dis);
  scatter2<<<2 * eb, 256, 0, stream>>>(di_t, di_r, cur_dis, cur_drug, sorted_t, sorted_r, eb);

  // gather-side aggregation, one wave per destination node (no atomics)
  aggregate<1><<<(N_DIS + 3) / 4,  256, 0, stream>>>(Xs_t, Xd_t, si_t, sorted_t, offs_dis,  cnt_dis,  gate,    attn_t, aggr_dis,  N_DIS);
  aggregate<0><<<(N_DRUG + 3) / 4, 256, 0, stream>>>(Xs_r, Xd_r, si_r, sorted_r, offs_drug, cnt_drug, nullptr, attn_r, aggr_drug, N_DRUG);

  // output linears (softmax normalization already fused into aggregation)
  gemm128<0><<<grid(nt_drug), 256, 0, stream>>>(aggr_drug, Wo_drug, nullptr, nullptr, bo_drug, out_drug, nullptr, N_DRUG, nt_drug);
  gemm128<0><<<grid(nt_dis),  256, 0, stream>>>(aggr_dis,  Wo_dis,  nullptr, nullptr, bo_dis,  out_dis,  nullptr, N_DIS,  nt_dis);
}

// Round 4
// 441.840 us; speedup vs baseline: 2.7083x; 1.0421x over previous
//
#include <hip/hip_runtime.h>
#include <hip/hip_bf16.h>
#include <math.h>

#define N_DRUG 50000
#define N_DIS  20000
#define NE     250000

// scan geometry: segment 0 = cnt_dis (20000), segment 1 = cnt_drug (50000)
#define NB0 79     // ceil(20000/256)
#define NBT 275    // NB0 + ceil(50000/256)

typedef __bf16 bf16x8 __attribute__((ext_vector_type(8)));
typedef __bf16 bf16x4 __attribute__((ext_vector_type(4)));
typedef __bf16 bf16x2 __attribute__((ext_vector_type(2)));
typedef float  f32x4  __attribute__((ext_vector_type(4)));
typedef float  f32x2  __attribute__((ext_vector_type(2)));

// Fast gelu: erf via Abramowitz-Stegun 7.1.27 (|erf err| <= 5e-4), with the
// 1/sqrt(2) of gelu folded into the coefficients. ~12 VALU ops, branchless.
// gelu(x) = 0.5*x*(1+erf(x/sqrt2)); for x>=0: 1+erf = 2 - p^-4, else p^-4.
__device__ __forceinline__ float gelu_fast(float x) {
  float ax = fabsf(x);
  float t = fmaf(ax, 0.019527f, 3.43654e-4f);
  t = fmaf(ax, t, 0.1151945f);
  t = fmaf(ax, t, 0.1968564f);
  float p = fmaf(ax, t, 1.0f);
  float p2 = p * p;
  float p4 = p2 * p2;
  float r = 1.0f / p4;
  float sel = (x >= 0.f) ? (2.0f - r) : r;
  return 0.5f * x * sel;
}

// ---------------------------------------------------------------------------
// Fused multi-segment [M,128] @ [128,128] GEMM, one 64-row tile per block.
// Segment descriptor picks A/W/bias/out per tile range. bf16 MFMA 16x16x32.
// AIN_BF16: A is bf16 (direct LDS copy). OUT_BF16: store bf16 else f32.
// ---------------------------------------------------------------------------
struct Seg4 {
  const void* A[4];
  const float* W[4];
  const float* bias[4];
  void* out[4];
  int M[4];
  int tstart[4];
};

template <int AIN_BF16, int OUT_BF16>
__global__ __launch_bounds__(256)
void gemm_multi(Seg4 d)
{
  __shared__ __bf16 Alds[64][136];
  __shared__ __bf16 Wt[128][136];   // W transposed: Wt[n][k]

  const int t = blockIdx.x;
  const int sidx = (t >= d.tstart[3]) ? 3 : (t >= d.tstart[2]) ? 2
                 : (t >= d.tstart[1]) ? 1 : 0;
  const float* W = d.W[sidx];
  const float* bias = d.bias[sidx];
  const int M = d.M[sidx];
  const int r0 = (t - d.tstart[sidx]) << 6;
  const int tid = threadIdx.x;

  for (int idx = tid; idx < 16384; idx += 256) {
    int k = idx >> 7, n = idx & 127;
    Wt[n][k] = (__bf16)W[idx];
  }

  if (AIN_BF16) {
    const __bf16* A = (const __bf16*)d.A[sidx];
    for (int i = tid; i < 1024; i += 256) {
      int row = i >> 4, c8 = i & 15;
      int gr = r0 + row;
      bf16x8 v = {(__bf16)0.f,(__bf16)0.f,(__bf16)0.f,(__bf16)0.f,
                  (__bf16)0.f,(__bf16)0.f,(__bf16)0.f,(__bf16)0.f};
      if (gr < M) v = *(const bf16x8*)(A + (long)gr * 128 + c8 * 8);
      *(bf16x8*)&Alds[row][c8 * 8] = v;
    }
  } else {
    const float* A = (const float*)d.A[sidx];
    for (int i = tid; i < 2048; i += 256) {
      int row = i >> 5, c4 = i & 31;
      int gr = r0 + row;
      f32x4 v = {0.f, 0.f, 0.f, 0.f};
      if (gr < M) v = ((const f32x4*)A)[(long)gr * 32 + c4];
      bf16x4 b;
      #pragma unroll
      for (int j = 0; j < 4; ++j) b[j] = (__bf16)v[j];
      *(bf16x4*)&Alds[row][c4 * 4] = b;
    }
  }
  __syncthreads();

  const int wv = tid >> 6, lane = tid & 63;
  const int m16 = lane & 15, quad = lane >> 4;
  f32x4 acc[8];
  #pragma unroll
  for (int ct = 0; ct < 8; ++ct) acc[ct] = (f32x4){0.f, 0.f, 0.f, 0.f};
  const int arow = wv * 16 + m16;
  #pragma unroll
  for (int kt = 0; kt < 4; ++kt) {
    bf16x8 a = *(const bf16x8*)&Alds[arow][kt * 32 + quad * 8];
    #pragma unroll
    for (int ct = 0; ct < 8; ++ct) {
      bf16x8 b = *(const bf16x8*)&Wt[ct * 16 + m16][kt * 32 + quad * 8];
      acc[ct] = __builtin_amdgcn_mfma_f32_16x16x32_bf16(a, b, acc[ct], 0, 0, 0);
    }
  }

  // C/D layout: col=lane&15, row=quad*4+reg
  const int rb = r0 + wv * 16 + quad * 4;
  #pragma unroll
  for (int ct = 0; ct < 8; ++ct) {
    int col = ct * 16 + m16;
    float bv = bias[col];
    #pragma unroll
    for (int rg = 0; rg < 4; ++rg) {
      int gr = rb + rg;
      if (gr < M) {
        float v = acc[ct][rg] + bv;
        if (OUT_BF16) ((__bf16*)d.out[sidx])[(long)gr * 128 + col] = (__bf16)v;
        else          ((float*)d.out[sidx])[(long)gr * 128 + col] = v;
      }
    }
  }
}

// ---------------------------------------------------------------------------
// Edge gate: outB = sigmoid( gelu(ea@Wg1+bg1) @ W2 + bias ), bf16 out.
// Layer-1 (K=8) fused into A-staging with Wg1/bg1 hoisted to registers
// (per-thread column block c4i = tid&31 is loop-invariant). One tile/block.
// ---------------------------------------------------------------------------
__global__ __launch_bounds__(256)
void gemm_gate(const float* __restrict__ EA, const float* __restrict__ W2,
               const float* __restrict__ Wg1, const float* __restrict__ bg1,
               const float* __restrict__ bias, __bf16* __restrict__ outB)
{
  __shared__ __bf16 Alds[64][136];
  __shared__ __bf16 Wt[128][136];
  const int tid = threadIdx.x;
  const int c4i = tid & 31;

  f32x4 wreg[8];
  #pragma unroll
  for (int k = 0; k < 8; ++k) wreg[k] = ((const f32x4*)Wg1)[k * 32 + c4i];
  f32x4 bgv = ((const f32x4*)bg1)[c4i];

  for (int idx = tid; idx < 16384; idx += 256) {
    int k = idx >> 7, n = idx & 127;
    Wt[n][k] = (__bf16)W2[idx];
  }

  const int r0 = blockIdx.x << 6;
  const int rowb = tid >> 5;
  #pragma unroll
  for (int j = 0; j < 8; ++j) {
    int row = rowb + 8 * j;
    int gr = r0 + row;
    bf16x4 b;
    if (gr < NE) {
      const f32x4* ea4 = (const f32x4*)(EA + (long)gr * 8);
      f32x4 e0 = ea4[0], e1 = ea4[1];
      f32x4 acc = bgv;
      #pragma unroll
      for (int k = 0; k < 4; ++k) {
        #pragma unroll
        for (int q = 0; q < 4; ++q) acc[q] = fmaf(e0[k], wreg[k][q], acc[q]);
      }
      #pragma unroll
      for (int k = 0; k < 4; ++k) {
        #pragma unroll
        for (int q = 0; q < 4; ++q) acc[q] = fmaf(e1[k], wreg[4 + k][q], acc[q]);
      }
      #pragma unroll
      for (int q = 0; q < 4; ++q) b[q] = (__bf16)gelu_fast(acc[q]);
    } else {
      #pragma unroll
      for (int q = 0; q < 4; ++q) b[q] = (__bf16)0.f;
    }
    *(bf16x4*)&Alds[row][c4i * 4] = b;
  }
  __syncthreads();

  const int wv = tid >> 6, lane = tid & 63;
  const int m16 = lane & 15, quad = lane >> 4;
  f32x4 acc[8];
  #pragma unroll
  for (int ct = 0; ct < 8; ++ct) acc[ct] = (f32x4){0.f, 0.f, 0.f, 0.f};
  const int arow = wv * 16 + m16;
  #pragma unroll
  for (int kt = 0; kt < 4; ++kt) {
    bf16x8 a = *(const bf16x8*)&Alds[arow][kt * 32 + quad * 8];
    #pragma unroll
    for (int ct = 0; ct < 8; ++ct) {
      bf16x8 b = *(const bf16x8*)&Wt[ct * 16 + m16][kt * 32 + quad * 8];
      acc[ct] = __builtin_amdgcn_mfma_f32_16x16x32_bf16(a, b, acc[ct], 0, 0, 0);
    }
  }
  const int rb = r0 + wv * 16 + quad * 4;
  #pragma unroll
  for (int ct = 0; ct < 8; ++ct) {
    int col = ct * 16 + m16;
    float bv = bias[col];
    #pragma unroll
    for (int rg = 0; rg < 4; ++rg) {
      int gr = rb + rg;
      if (gr < NE) {
        float v = acc[ct][rg] + bv;
        float g = 1.0f / (1.0f + __expf(-v));
        outB[(long)gr * 128 + col] = (__bf16)g;
      }
    }
  }
}

// ---------------------------------------------------------------------------
// Counting sort of edges by destination node (both edge types per launch).
// ---------------------------------------------------------------------------
__global__ __launch_bounds__(256)
void histo2(const int* __restrict__ di_t, const int* __restrict__ di_r,
            int* __restrict__ cnt_dis, int* __restrict__ cnt_drug, int half) {
  int b = blockIdx.x;
  if (b < half) {
    int i = b * 256 + threadIdx.x;
    if (i < NE) atomicAdd(&cnt_dis[di_t[i]], 1);
  } else {
    int i = (b - half) * 256 + threadIdx.x;
    if (i < NE) atomicAdd(&cnt_drug[di_r[i]], 1);
  }
}

__global__ __launch_bounds__(256)
void scatter2(const int* __restrict__ di_t, const int* __restrict__ di_r,
              int* __restrict__ cur_dis, int* __restrict__ cur_drug,
              int* __restrict__ sorted_t, int* __restrict__ sorted_r, int half) {
  int b = blockIdx.x;
  if (b < half) {
    int i = b * 256 + threadIdx.x;
    if (i < NE) sorted_t[atomicAdd(&cur_dis[di_t[i]], 1)] = i;
  } else {
    int i = (b - half) * 256 + threadIdx.x;
    if (i < NE) sorted_r[atomicAdd(&cur_drug[di_r[i]], 1)] = i;
  }
}

// ---------------------------------------------------------------------------
// Device-wide segmented exclusive scan over concatenated cnt_dis||cnt_drug.
// ---------------------------------------------------------------------------
__device__ __forceinline__ void seg_geom(int b, int& base, int& n, int& lb) {
  if (b < NB0) { base = 0;     n = 20000; lb = b; }
  else         { base = 20000; n = 50000; lb = b - NB0; }
}

__global__ __launch_bounds__(256)
void scan_partial(const int* __restrict__ cnt, int* __restrict__ bsum) {
  __shared__ int sh[256];
  int b = blockIdx.x, t = threadIdx.x;
  int base, n, lb; seg_geom(b, base, n, lb);
  int i = lb * 256 + t;
  sh[t] = (i < n) ? cnt[base + i] : 0;
  __syncthreads();
  for (int d = 1; d < 256; d <<= 1) {
    int vv = (t >= d) ? sh[t - d] : 0;
    __syncthreads();
    sh[t] += vv;
    __syncthreads();
  }
  if (t == 255) bsum[b] = sh[255];
}

__global__ __launch_bounds__(512)
void scan_block(const int* __restrict__ bsum, int* __restrict__ bexc) {
  __shared__ int v[512];
  __shared__ int f[512];
  int t = threadIdx.x;
  int own = (t < NBT) ? bsum[t] : 0;
  v[t] = own;
  f[t] = (t == 0 || t == NB0 || t >= NBT) ? 1 : 0;
  __syncthreads();
  for (int d = 1; d < 512; d <<= 1) {
    int vv = 0, ff = 1;
    if (t >= d) { vv = v[t - d]; ff = f[t - d]; }
    __syncthreads();
    if (t >= d && !f[t]) { v[t] += vv; f[t] |= ff; }
    __syncthreads();
  }
  if (t < NBT) bexc[t] = v[t] - own;   // exclusive within segment
}

__global__ __launch_bounds__(256)
void scan_final(const int* __restrict__ cnt, const int* __restrict__ bexc,
                int* __restrict__ offs, int* __restrict__ cursor) {
  __shared__ int sh[256];
  int b = blockIdx.x, t = threadIdx.x;
  int base, n, lb; seg_geom(b, base, n, lb);
  int i = lb * 256 + t;
  int own = (i < n) ? cnt[base + i] : 0;
  sh[t] = own;
  __syncthreads();
  for (int d = 1; d < 256; d <<= 1) {
    int vv = (t >= d) ? sh[t - d] : 0;
    __syncthreads();
    sh[t] += vv;
    __syncthreads();
  }
  int off = bexc[b] + sh[t] - own;
  if (i < n) { offs[base + i] = off; cursor[base + i] = off; }
}

// ---------------------------------------------------------------------------
// Gather-side aggregation: one 64-lane wave per destination node; lane owns
// channels {2*lane, 2*lane+1}. Data (xs, gate) software-pipelined one edge
// ahead along with the index chain. Softmax normalization fused in epilogue.
// ---------------------------------------------------------------------------
template <int HASGATE>
__global__ __launch_bounds__(256)
void aggregate(const __bf16* __restrict__ Xs, const __bf16* __restrict__ Xd,
               const int* __restrict__ si, const int* __restrict__ sorted,
               const int* __restrict__ offs, const int* __restrict__ cnt,
               const __bf16* __restrict__ gate, const float* __restrict__ attn,
               __bf16* __restrict__ out, int n)
{
  int w = (int)((blockIdx.x * 256 + threadIdx.x) >> 6);
  if (w >= n) return;
  const int lane = threadIdx.x & 63;
  const int c = lane * 2;

  f32x2 at = *(const f32x2*)(attn + c);
  bf16x2 xdb = *(const bf16x2*)(Xd + (long)w * 128 + c);
  const float xd0 = (float)xdb[0], xd1 = (float)xdb[1];
  const int start = offs[w];
  const int m = cnt[w];

  float n0 = 0.f, n1 = 0.f, den = 0.f;

  bf16x2 xs_n = {(__bf16)0.f, (__bf16)0.f};
  bf16x2 g_n  = {(__bf16)0.f, (__bf16)0.f};
  if (m > 0) {
    int e = sorted[start];
    int s = si[e];
    xs_n = *(const bf16x2*)(Xs + (long)s * 128 + c);
    if (HASGATE) g_n = *(const bf16x2*)(gate + (long)e * 128 + c);
  }
  for (int j = 0; j < m; ++j) {
    bf16x2 xsb = xs_n, gb = g_n;
    if (j + 1 < m) {
      int e = sorted[start + j + 1];
      int s = si[e];
      xs_n = *(const bf16x2*)(Xs + (long)s * 128 + c);
      if (HASGATE) g_n = *(const bf16x2*)(gate + (long)e * 128 + c);
    }
    float xs0 = (float)xsb[0], xs1 = (float)xsb[1];
    float m0 = xs0 + xd0, m1 = xs1 + xd1;
    if (HASGATE) { m0 *= (float)gb[0]; m1 *= (float)gb[1]; }
    float part = (xs0 * xd0 + xs1 * xd1) * 0.17677669529663687f
               + m0 * at[0] + m1 * at[1];
    part += __shfl_xor(part, 1);
    part += __shfl_xor(part, 2);
    part += __shfl_xor(part, 4);
    part += __shfl_xor(part, 8);
    float ex = __expf(part);
    n0 += m0 * ex;
    n1 += m1 * ex;
    den += ex;
  }

  float r = 1.0f / (den + 1e-16f);
  bf16x2 o;
  o[0] = (__bf16)(n0 * r);
  o[1] = (__bf16)(n1 * r);
  *(bf16x2*)(out + (long)w * 128 + c) = o;
}

// ---------------------------------------------------------------------------
extern "C" void kernel_launch(void* const* d_in, const int* in_sizes, int n_in,
                              void* d_out, int out_size, void* d_ws, size_t ws_size,
                              hipStream_t stream)
{
  const float* x_drug  = (const float*)d_in[0];
  const float* x_dis   = (const float*)d_in[1];
  const float* ea      = (const float*)d_in[2];
  const int*   si_t    = (const int*)d_in[3];
  const int*   di_t    = (const int*)d_in[4];
  const int*   si_r    = (const int*)d_in[5];
  const int*   di_r    = (const int*)d_in[6];
  const float* Ws_t    = (const float*)d_in[7];
  const float* bs_t    = (const float*)d_in[8];
  const float* Wd_t    = (const float*)d_in[9];
  const float* bd_t    = (const float*)d_in[10];
  const float* attn_t  = (const float*)d_in[11];
  const float* Wg1     = (const float*)d_in[12];
  const float* bg1     = (const float*)d_in[13];
  const float* Wg2     = (const float*)d_in[14];
  const float* bg2     = (const float*)d_in[15];
  const float* Ws_r    = (const float*)d_in[16];
  const float* bs_r    = (const float*)d_in[17];
  const float* Wd_r    = (const float*)d_in[18];
  const float* bd_r    = (const float*)d_in[19];
  const float* attn_r  = (const float*)d_in[20];
  const float* Wo_drug = (const float*)d_in[21];
  const float* bo_drug = (const float*)d_in[22];
  const float* Wo_dis  = (const float*)d_in[23];
  const float* bo_dis  = (const float*)d_in[24];

  // workspace layout (~108 MB); X/aggr/gate tensors bf16
  __bf16* wsb      = (__bf16*)d_ws;
  __bf16* Xs_t     = wsb;                  // 50000*128 (reused as aggr_drug)
  __bf16* Xd_t     = Xs_t + 6400000;       // 20000*128
  __bf16* Xs_r     = Xd_t + 2560000;       // 20000*128
  __bf16* Xd_r     = Xs_r + 2560000;       // 50000*128
  __bf16* aggr_dis = Xd_r + 6400000;       // 20000*128
  __bf16* gate     = aggr_dis + 2560000;   // 250000*128
  int* cnt_dis    = (int*)(gate + (long)NE * 128);  // 20000  --+ contiguous:
  int* cnt_drug   = cnt_dis + 20000;       // 50000             | zeroed+scanned
  int* offs_dis   = cnt_drug + 50000;      // 20000             | as one region
  int* offs_drug  = offs_dis + 20000;      // 50000             |
  int* cur_dis    = offs_drug + 50000;     // 20000             |
  int* cur_drug   = cur_dis + 20000;       // 50000           --+
  int* sorted_t   = cur_drug + 50000;      // 250000
  int* sorted_r   = sorted_t + 250000;     // 250000
  int* bsum       = sorted_r + 250000;     // 275
  int* bexc       = bsum + 512;            // 275

  __bf16* aggr_drug = Xs_t;                // safe: Xs_t dead after treats agg

  float* out_drug = (float*)d_out;
  float* out_dis  = out_drug + (long)N_DRUG * 128;

  hipMemsetAsync(cnt_dis, 0, 70000 * sizeof(int), stream);

  const int eb = (NE + 255) / 256;         // 977

  // counting sort by destination (both convs), device-wide 3-phase scan
  histo2<<<2 * eb, 256, 0, stream>>>(di_t, di_r, cnt_dis, cnt_drug, eb);
  scan_partial<<<NBT, 256, 0, stream>>>(cnt_dis, bsum);
  scan_block<<<1, 512, 0, stream>>>(bsum, bexc);
  scan_final<<<NBT, 256, 0, stream>>>(cnt_dis, bexc, offs_dis, cur_dis);
  scatter2<<<2 * eb, 256, 0, stream>>>(di_t, di_r, cur_dis, cur_drug, sorted_t, sorted_r, eb);

  // 4 node transforms fused into one launch: X = x @ W + b, bf16 out
  // tiles: 782 + 313 + 313 + 782 = 2190
  Seg4 nd;
  nd.A[0] = x_drug; nd.W[0] = Ws_t; nd.bias[0] = bs_t; nd.out[0] = Xs_t; nd.M[0] = N_DRUG; nd.tstart[0] = 0;
  nd.A[1] = x_dis;  nd.W[1] = Wd_t; nd.bias[1] = bd_t; nd.out[1] = Xd_t; nd.M[1] = N_DIS;  nd.tstart[1] = 782;
  nd.A[2] = x_dis;  nd.W[2] = Ws_r; nd.bias[2] = bs_r; nd.out[2] = Xs_r; nd.M[2] = N_DIS;  nd.tstart[2] = 1095;
  nd.A[3] = x_drug; nd.W[3] = Wd_r; nd.bias[3] = bd_r; nd.out[3] = Xd_r; nd.M[3] = N_DRUG; nd.tstart[3] = 1408;
  gemm_multi<0, 1><<<2190, 256, 0, stream>>>(nd);

  // edge gate (one tile per block)
  gemm_gate<<<(NE + 63) / 64, 256, 0, stream>>>(ea, Wg2, Wg1, bg1, bg2, gate);

  // gather-side aggregation, one wave per destination node (no atomics)
  aggregate<1><<<(N_DIS + 3) / 4,  256, 0, stream>>>(Xs_t, Xd_t, si_t, sorted_t, offs_dis,  cnt_dis,  gate,    attn_t, aggr_dis,  N_DIS);
  aggregate<0><<<(N_DRUG + 3) / 4, 256, 0, stream>>>(Xs_r, Xd_r, si_r, sorted_r, offs_drug, cnt_drug, nullptr, attn_r, aggr_drug, N_DRUG);

  // 2 output linears fused into one launch: out = aggr @ Wo + bo, f32 out
  Seg4 od;
  od.A[0] = aggr_drug; od.W[0] = Wo_drug; od.bias[0] = bo_drug; od.out[0] = out_drug; od.M[0] = N_DRUG; od.tstart[0] = 0;
  od.A[1] = aggr_dis;  od.W[1] = Wo_dis;  od.bias[1] = bo_dis;  od.out[1] = out_dis;  od.M[1] = N_DIS;  od.tstart[1] = 782;
  od.A[2] = od.A[1];   od.W[2] = od.W[1]; od.bias[2] = od.bias[1]; od.out[2] = od.out[1]; od.M[2] = N_DIS; od.tstart[2] = 0x7fffffff;
  od.A[3] = od.A[1];   od.W[3] = od.W[1]; od.bias[3] = od.bias[1]; od.out[3] = od.out[1]; od.M[3] = N_DIS; od.tstart[3] = 0x7fffffff;
  gemm_multi<1, 0><<<1095, 256, 0, stream>>>(od);
}

// Round 5
// 405.576 us; speedup vs baseline: 2.9504x; 1.0894x over previous
//
#include <hip/hip_runtime.h>
#include <hip/hip_bf16.h>
#include <math.h>

#define N_DRUG 50000
#define N_DIS  20000
#define NE     250000

// scan geometry: segment 0 = cnt_dis (20000), segment 1 = cnt_drug (50000)
#define NB0 79     // ceil(20000/256)
#define NBT 275    // NB0 + ceil(50000/256)

typedef __bf16 bf16x8 __attribute__((ext_vector_type(8)));
typedef __bf16 bf16x4 __attribute__((ext_vector_type(4)));
typedef __bf16 bf16x2 __attribute__((ext_vector_type(2)));
typedef float  f32x4  __attribute__((ext_vector_type(4)));
typedef float  f32x2  __attribute__((ext_vector_type(2)));

__device__ __forceinline__ bf16x8 bz8() {
  bf16x8 v;
  #pragma unroll
  for (int j = 0; j < 8; ++j) v[j] = (__bf16)0.f;
  return v;
}

// Fast gelu: erf via Abramowitz-Stegun 7.1.27 (|erf err| <= 5e-4), 1/sqrt(2)
// folded into coefficients. gelu(x)=0.5*x*(2-p^-4) for x>=0, 0.5*x*p^-4 else.
__device__ __forceinline__ float gelu_fast(float x) {
  float ax = fabsf(x);
  float t = fmaf(ax, 0.019527f, 3.43654e-4f);
  t = fmaf(ax, t, 0.1151945f);
  t = fmaf(ax, t, 0.1968564f);
  float p = fmaf(ax, t, 1.0f);
  float p2 = p * p;
  float p4 = p2 * p2;
  float r = 1.0f / p4;
  float sel = (x >= 0.f) ? (2.0f - r) : r;
  return 0.5f * x * sel;
}

// ---------------------------------------------------------------------------
// Persistent multi-segment [M,128] @ [128,128] GEMM.
// Per-segment block partition (bstart[5]); each block stages its segment's W
// to LDS ONCE, then grid-strides tiles. A-fragments are loaded directly from
// global into registers (each A element feeds exactly one lane-fragment slot
// -> LDS staging buys nothing), so there are NO barriers in the tile loop.
// ---------------------------------------------------------------------------
struct Seg {
  const void* A[4];
  const float* W[4];
  const float* bias[4];
  void* out[4];
  int M[4];
  int bstart[5];
};

template <int AIN_BF16, int OUT_BF16>
__global__ __launch_bounds__(256)
void gemm_seg(Seg d)
{
  __shared__ __bf16 Wt[128][136];   // W transposed: Wt[n][k]

  const int b = blockIdx.x;
  const int sidx = (b >= d.bstart[3]) ? 3 : (b >= d.bstart[2]) ? 2
                 : (b >= d.bstart[1]) ? 1 : 0;
  const int nb = d.bstart[sidx + 1] - d.bstart[sidx];
  const int lb = b - d.bstart[sidx];
  const float* W = d.W[sidx];
  const float* bias = d.bias[sidx];
  const int M = d.M[sidx];
  const int ntiles = (M + 63) >> 6;
  const int tid = threadIdx.x;
  const int wv = tid >> 6, lane = tid & 63;
  const int m16 = lane & 15, quad = lane >> 4;

  for (int idx = tid; idx < 16384; idx += 256) {
    int k = idx >> 7, n = idx & 127;
    Wt[n][k] = (__bf16)W[idx];
  }
  __syncthreads();   // the only barrier: Wt visible to all waves

  float bv[8];
  #pragma unroll
  for (int ct = 0; ct < 8; ++ct) bv[ct] = bias[ct * 16 + m16];

  for (int t = lb; t < ntiles; t += nb) {
    const int r0 = t << 6;
    const int arow = r0 + wv * 16 + m16;
    const bool ok = arow < M;

    bf16x8 afr[4];
    if (AIN_BF16) {
      const __bf16* ap = (const __bf16*)d.A[sidx] + (long)arow * 128 + quad * 8;
      #pragma unroll
      for (int kt = 0; kt < 4; ++kt)
        afr[kt] = ok ? *(const bf16x8*)(ap + kt * 32) : bz8();
    } else {
      const float* ap = (const float*)d.A[sidx] + (long)arow * 128 + quad * 8;
      #pragma unroll
      for (int kt = 0; kt < 4; ++kt) {
        bf16x8 v = bz8();
        if (ok) {
          f32x4 lo = *(const f32x4*)(ap + kt * 32);
          f32x4 hi = *(const f32x4*)(ap + kt * 32 + 4);
          #pragma unroll
          for (int j = 0; j < 4; ++j) { v[j] = (__bf16)lo[j]; v[4 + j] = (__bf16)hi[j]; }
        }
        afr[kt] = v;
      }
    }

    f32x4 acc[8];
    #pragma unroll
    for (int ct = 0; ct < 8; ++ct) acc[ct] = (f32x4){0.f, 0.f, 0.f, 0.f};
    #pragma unroll
    for (int kt = 0; kt < 4; ++kt) {
      #pragma unroll
      for (int ct = 0; ct < 8; ++ct) {
        bf16x8 bfr = *(const bf16x8*)&Wt[ct * 16 + m16][kt * 32 + quad * 8];
        acc[ct] = __builtin_amdgcn_mfma_f32_16x16x32_bf16(afr[kt], bfr, acc[ct], 0, 0, 0);
      }
    }

    // C/D layout: col=lane&15, row=quad*4+reg
    const int rb = r0 + wv * 16 + quad * 4;
    #pragma unroll
    for (int ct = 0; ct < 8; ++ct) {
      const int col = ct * 16 + m16;
      #pragma unroll
      for (int rg = 0; rg < 4; ++rg) {
        int gr = rb + rg;
        if (gr < M) {
          float v = acc[ct][rg] + bv[ct];
          if (OUT_BF16) ((__bf16*)d.out[sidx])[(long)gr * 128 + col] = (__bf16)v;
          else          ((float*)d.out[sidx])[(long)gr * 128 + col] = v;
        }
      }
    }
  }
}

// ---------------------------------------------------------------------------
// Edge gate: out = sigmoid( gelu(ea@Wg1+bg1) @ W2 + bg2 ), bf16 out.
// Persistent blocks; W2 staged to LDS once. Layer-1 is a zero-padded-K MFMA:
// A-frag k=quad*8+j, so quad-0 lanes carry the 8 real ea values, other quads
// zero; Wg1 B-fragments hoisted into registers. gelu applied in C-layout,
// redistributed to A-frag layout via a WAVE-PRIVATE LDS stripe (rows
// [wv*16,wv*16+16) touched only by wave wv) -> no __syncthreads in the loop.
// ---------------------------------------------------------------------------
__global__ __launch_bounds__(256)
void gate_kernel(const float* __restrict__ EA, const float* __restrict__ W2,
                 const float* __restrict__ Wg1, const float* __restrict__ bg1,
                 const float* __restrict__ bg2, __bf16* __restrict__ out)
{
  __shared__ __bf16 Wt[128][136];
  __shared__ __bf16 H[64][136];
  const int tid = threadIdx.x;
  const int wv = tid >> 6, lane = tid & 63;
  const int m16 = lane & 15, quad = lane >> 4;

  for (int idx = tid; idx < 16384; idx += 256) {
    int k = idx >> 7, n = idx & 127;
    Wt[n][k] = (__bf16)W2[idx];
  }
  __syncthreads();

  // layer-1 B-fragments: B[n=ct*16+m16][k=quad*8+j] = Wg1[k][n], k<8 real
  bf16x8 b1[8];
  #pragma unroll
  for (int ct = 0; ct < 8; ++ct) {
    bf16x8 v = bz8();
    if (quad == 0) {
      #pragma unroll
      for (int j = 0; j < 8; ++j) v[j] = (__bf16)Wg1[j * 128 + ct * 16 + m16];
    }
    b1[ct] = v;
  }
  float b1v[8], b2v[8];
  #pragma unroll
  for (int ct = 0; ct < 8; ++ct) {
    b1v[ct] = bg1[ct * 16 + m16];
    b2v[ct] = bg2[ct * 16 + m16];
  }

  const int ntiles = (NE + 63) >> 6;   // 3907
  for (int t = blockIdx.x; t < ntiles; t += gridDim.x) {
    const int r0 = t << 6;
    const int arow = r0 + wv * 16 + m16;

    // layer-1 A-frag: quad 0 holds the ea row (k=0..7), rest zero
    bf16x8 a1 = bz8();
    if (quad == 0 && arow < NE) {
      f32x4 e0 = *(const f32x4*)(EA + (long)arow * 8);
      f32x4 e1 = *(const f32x4*)(EA + (long)arow * 8 + 4);
      #pragma unroll
      for (int j = 0; j < 4; ++j) { a1[j] = (__bf16)e0[j]; a1[4 + j] = (__bf16)e1[j]; }
    }
    f32x4 h[8];
    #pragma unroll
    for (int ct = 0; ct < 8; ++ct)
      h[ct] = __builtin_amdgcn_mfma_f32_16x16x32_bf16(a1, b1[ct], (f32x4){0.f,0.f,0.f,0.f}, 0, 0, 0);

    // bias + gelu in C-layout, store bf16 into wave-private H stripe
    const int hr = wv * 16 + quad * 4;
    #pragma unroll
    for (int ct = 0; ct < 8; ++ct) {
      const int col = ct * 16 + m16;
      #pragma unroll
      for (int rg = 0; rg < 4; ++rg)
        H[hr + rg][col] = (__bf16)gelu_fast(h[ct][rg] + b1v[ct]);
    }
    // in-wave write->read fence (DS pipe is in-order per wave; this stops
    // compiler reordering and drains the writes)
    asm volatile("s_waitcnt lgkmcnt(0)" ::: "memory");

    bf16x8 afr[4];
    #pragma unroll
    for (int kt = 0; kt < 4; ++kt)
      afr[kt] = *(const bf16x8*)&H[wv * 16 + m16][kt * 32 + quad * 8];
    asm volatile("" ::: "memory");  // keep next iter's H writes below these reads

    f32x4 acc[8];
    #pragma unroll
    for (int ct = 0; ct < 8; ++ct) acc[ct] = (f32x4){0.f, 0.f, 0.f, 0.f};
    #pragma unroll
    for (int kt = 0; kt < 4; ++kt) {
      #pragma unroll
      for (int ct = 0; ct < 8; ++ct) {
        bf16x8 bfr = *(const bf16x8*)&Wt[ct * 16 + m16][kt * 32 + quad * 8];
        acc[ct] = __builtin_amdgcn_mfma_f32_16x16x32_bf16(afr[kt], bfr, acc[ct], 0, 0, 0);
      }
    }

    const int rb = r0 + wv * 16 + quad * 4;
    #pragma unroll
    for (int ct = 0; ct < 8; ++ct) {
      const int col = ct * 16 + m16;
      #pragma unroll
      for (int rg = 0; rg < 4; ++rg) {
        int gr = rb + rg;
        if (gr < NE) {
          float v = acc[ct][rg] + b2v[ct];
          out[(long)gr * 128 + col] = (__bf16)(1.0f / (1.0f + __expf(-v)));
        }
      }
    }
  }
}

// ---------------------------------------------------------------------------
// Counting sort of edges by destination node (both edge types per launch).
// ---------------------------------------------------------------------------
__global__ __launch_bounds__(256)
void histo2(const int* __restrict__ di_t, const int* __restrict__ di_r,
            int* __restrict__ cnt_dis, int* __restrict__ cnt_drug, int half) {
  int b = blockIdx.x;
  if (b < half) {
    int i = b * 256 + threadIdx.x;
    if (i < NE) atomicAdd(&cnt_dis[di_t[i]], 1);
  } else {
    int i = (b - half) * 256 + threadIdx.x;
    if (i < NE) atomicAdd(&cnt_drug[di_r[i]], 1);
  }
}

__global__ __launch_bounds__(256)
void scatter2(const int* __restrict__ di_t, const int* __restrict__ di_r,
              int* __restrict__ cur_dis, int* __restrict__ cur_drug,
              int* __restrict__ sorted_t, int* __restrict__ sorted_r, int half) {
  int b = blockIdx.x;
  if (b < half) {
    int i = b * 256 + threadIdx.x;
    if (i < NE) sorted_t[atomicAdd(&cur_dis[di_t[i]], 1)] = i;
  } else {
    int i = (b - half) * 256 + threadIdx.x;
    if (i < NE) sorted_r[atomicAdd(&cur_drug[di_r[i]], 1)] = i;
  }
}

// ---------------------------------------------------------------------------
// Device-wide segmented exclusive scan over concatenated cnt_dis||cnt_drug.
// ---------------------------------------------------------------------------
__device__ __forceinline__ void seg_geom(int b, int& base, int& n, int& lb) {
  if (b < NB0) { base = 0;     n = 20000; lb = b; }
  else         { base = 20000; n = 50000; lb = b - NB0; }
}

__global__ __launch_bounds__(256)
void scan_partial(const int* __restrict__ cnt, int* __restrict__ bsum) {
  __shared__ int sh[256];
  int b = blockIdx.x, t = threadIdx.x;
  int base, n, lb; seg_geom(b, base, n, lb);
  int i = lb * 256 + t;
  sh[t] = (i < n) ? cnt[base + i] : 0;
  __syncthreads();
  for (int d = 1; d < 256; d <<= 1) {
    int vv = (t >= d) ? sh[t - d] : 0;
    __syncthreads();
    sh[t] += vv;
    __syncthreads();
  }
  if (t == 255) bsum[b] = sh[255];
}

__global__ __launch_bounds__(512)
void scan_block(const int* __restrict__ bsum, int* __restrict__ bexc) {
  __shared__ int v[512];
  __shared__ int f[512];
  int t = threadIdx.x;
  int own = (t < NBT) ? bsum[t] : 0;
  v[t] = own;
  f[t] = (t == 0 || t == NB0 || t >= NBT) ? 1 : 0;
  __syncthreads();
  for (int d = 1; d < 512; d <<= 1) {
    int vv = 0, ff = 1;
    if (t >= d) { vv = v[t - d]; ff = f[t - d]; }
    __syncthreads();
    if (t >= d && !f[t]) { v[t] += vv; f[t] |= ff; }
    __syncthreads();
  }
  if (t < NBT) bexc[t] = v[t] - own;   // exclusive within segment
}

__global__ __launch_bounds__(256)
void scan_final(const int* __restrict__ cnt, const int* __restrict__ bexc,
                int* __restrict__ offs, int* __restrict__ cursor) {
  __shared__ int sh[256];
  int b = blockIdx.x, t = threadIdx.x;
  int base, n, lb; seg_geom(b, base, n, lb);
  int i = lb * 256 + t;
  int own = (i < n) ? cnt[base + i] : 0;
  sh[t] = own;
  __syncthreads();
  for (int d = 1; d < 256; d <<= 1) {
    int vv = (t >= d) ? sh[t - d] : 0;
    __syncthreads();
    sh[t] += vv;
    __syncthreads();
  }
  int off = bexc[b] + sh[t] - own;
  if (i < n) { offs[base + i] = off; cursor[base + i] = off; }
}

// ---------------------------------------------------------------------------
// Gather-side aggregation: one 64-lane wave per destination node; lane owns
// channels {2*lane, 2*lane+1}. Data (xs, gate) software-pipelined one edge
// ahead along with the index chain. Softmax normalization fused in epilogue.
// ---------------------------------------------------------------------------
template <int HASGATE>
__global__ __launch_bounds__(256)
void aggregate(const __bf16* __restrict__ Xs, const __bf16* __restrict__ Xd,
               const int* __restrict__ si, const int* __restrict__ sorted,
               const int* __restrict__ offs, const int* __restrict__ cnt,
               const __bf16* __restrict__ gate, const float* __restrict__ attn,
               __bf16* __restrict__ out, int n)
{
  int w = (int)((blockIdx.x * 256 + threadIdx.x) >> 6);
  if (w >= n) return;
  const int lane = threadIdx.x & 63;
  const int c = lane * 2;

  f32x2 at = *(const f32x2*)(attn + c);
  bf16x2 xdb = *(const bf16x2*)(Xd + (long)w * 128 + c);
  const float xd0 = (float)xdb[0], xd1 = (float)xdb[1];
  const int start = offs[w];
  const int m = cnt[w];

  float n0 = 0.f, n1 = 0.f, den = 0.f;

  bf16x2 xs_n = {(__bf16)0.f, (__bf16)0.f};
  bf16x2 g_n  = {(__bf16)0.f, (__bf16)0.f};
  if (m > 0) {
    int e = sorted[start];
    int s = si[e];
    xs_n = *(const bf16x2*)(Xs + (long)s * 128 + c);
    if (HASGATE) g_n = *(const bf16x2*)(gate + (long)e * 128 + c);
  }
  for (int j = 0; j < m; ++j) {
    bf16x2 xsb = xs_n, gb = g_n;
    if (j + 1 < m) {
      int e = sorted[start + j + 1];
      int s = si[e];
      xs_n = *(const bf16x2*)(Xs + (long)s * 128 + c);
      if (HASGATE) g_n = *(const bf16x2*)(gate + (long)e * 128 + c);
    }
    float xs0 = (float)xsb[0], xs1 = (float)xsb[1];
    float m0 = xs0 + xd0, m1 = xs1 + xd1;
    if (HASGATE) { m0 *= (float)gb[0]; m1 *= (float)gb[1]; }
    float part = (xs0 * xd0 + xs1 * xd1) * 0.17677669529663687f
               + m0 * at[0] + m1 * at[1];
    part += __shfl_xor(part, 1);
    part += __shfl_xor(part, 2);
    part += __shfl_xor(part, 4);
    part += __shfl_xor(part, 8);
    float ex = __expf(part);
    n0 += m0 * ex;
    n1 += m1 * ex;
    den += ex;
  }

  float r = 1.0f / (den + 1e-16f);
  bf16x2 o;
  o[0] = (__bf16)(n0 * r);
  o[1] = (__bf16)(n1 * r);
  *(bf16x2*)(out + (long)w * 128 + c) = o;
}

// ---------------------------------------------------------------------------
extern "C" void kernel_launch(void* const* d_in, const int* in_sizes, int n_in,
                              void* d_out, int out_size, void* d_ws, size_t ws_size,
                              hipStream_t stream)
{
  const float* x_drug  = (const float*)d_in[0];
  const float* x_dis   = (const float*)d_in[1];
  const float* ea      = (const float*)d_in[2];
  const int*   si_t    = (const int*)d_in[3];
  const int*   di_t    = (const int*)d_in[4];
  const int*   si_r    = (const int*)d_in[5];
  const int*   di_r    = (const int*)d_in[6];
  const float* Ws_t    = (const float*)d_in[7];
  const float* bs_t    = (const float*)d_in[8];
  const float* Wd_t    = (const float*)d_in[9];
  const float* bd_t    = (const float*)d_in[10];
  const float* attn_t  = (const float*)d_in[11];
  const float* Wg1     = (const float*)d_in[12];
  const float* bg1     = (const float*)d_in[13];
  const float* Wg2     = (const float*)d_in[14];
  const float* bg2     = (const float*)d_in[15];
  const float* Ws_r    = (const float*)d_in[16];
  const float* bs_r    = (const float*)d_in[17];
  const float* Wd_r    = (const float*)d_in[18];
  const float* bd_r    = (const float*)d_in[19];
  const float* attn_r  = (const float*)d_in[20];
  const float* Wo_drug = (const float*)d_in[21];
  const float* bo_drug = (const float*)d_in[22];
  const float* Wo_dis  = (const float*)d_in[23];
  const float* bo_dis  = (const float*)d_in[24];

  // workspace layout (~108 MB); X/aggr/gate tensors bf16
  __bf16* wsb      = (__bf16*)d_ws;
  __bf16* Xs_t     = wsb;                  // 50000*128 (reused as aggr_drug)
  __bf16* Xd_t     = Xs_t + 6400000;       // 20000*128
  __bf16* Xs_r     = Xd_t + 2560000;       // 20000*128
  __bf16* Xd_r     = Xs_r + 2560000;       // 50000*128
  __bf16* aggr_dis = Xd_r + 6400000;       // 20000*128
  __bf16* gate     = aggr_dis + 2560000;   // 250000*128
  int* cnt_dis    = (int*)(gate + (long)NE * 128);  // 20000  --+ contiguous:
  int* cnt_drug   = cnt_dis + 20000;       // 50000             | zeroed+scanned
  int* offs_dis   = cnt_drug + 50000;      // 20000             | as one region
  int* offs_drug  = offs_dis + 20000;      // 50000             |
  int* cur_dis    = offs_drug + 50000;     // 20000             |
  int* cur_drug   = cur_dis + 20000;       // 50000           --+
  int* sorted_t   = cur_drug + 50000;      // 250000
  int* sorted_r   = sorted_t + 250000;     // 250000
  int* bsum       = sorted_r + 250000;     // 275
  int* bexc       = bsum + 512;            // 275

  __bf16* aggr_drug = Xs_t;                // safe: Xs_t dead after treats agg

  float* out_drug = (float*)d_out;
  float* out_dis  = out_drug + (long)N_DRUG * 128;

  hipMemsetAsync(cnt_dis, 0, 70000 * sizeof(int), stream);

  const int eb = (NE + 255) / 256;         // 977

  // counting sort by destination (both convs), device-wide 3-phase scan
  histo2<<<2 * eb, 256, 0, stream>>>(di_t, di_r, cnt_dis, cnt_drug, eb);
  scan_partial<<<NBT, 256, 0, stream>>>(cnt_dis, bsum);
  scan_block<<<1, 512, 0, stream>>>(bsum, bexc);
  scan_final<<<NBT, 256, 0, stream>>>(cnt_dis, bexc, offs_dis, cur_dis);
  scatter2<<<2 * eb, 256, 0, stream>>>(di_t, di_r, cur_dis, cur_drug, sorted_t, sorted_r, eb);

  // 4 node transforms, persistent per-segment blocks (tiles 782/313/313/782)
  Seg nd;
  nd.A[0] = x_drug; nd.W[0] = Ws_t; nd.bias[0] = bs_t; nd.out[0] = Xs_t; nd.M[0] = N_DRUG;
  nd.A[1] = x_dis;  nd.W[1] = Wd_t; nd.bias[1] = bd_t; nd.out[1] = Xd_t; nd.M[1] = N_DIS;
  nd.A[2] = x_dis;  nd.W[2] = Ws_r; nd.bias[2] = bs_r; nd.out[2] = Xs_r; nd.M[2] = N_DIS;
  nd.A[3] = x_drug; nd.W[3] = Wd_r; nd.bias[3] = bd_r; nd.out[3] = Xd_r; nd.M[3] = N_DRUG;
  nd.bstart[0] = 0; nd.bstart[1] = 274; nd.bstart[2] = 384; nd.bstart[3] = 494; nd.bstart[4] = 768;
  gemm_seg<0, 1><<<768, 256, 0, stream>>>(nd);

  // edge gate, persistent blocks
  gate_kernel<<<768, 256, 0, stream>>>(ea, Wg2, Wg1, bg1, bg2, gate);

  // gather-side aggregation, one wave per destination node (no atomics)
  aggregate<1><<<(N_DIS + 3) / 4,  256, 0, stream>>>(Xs_t, Xd_t, si_t, sorted_t, offs_dis,  cnt_dis,  gate,    attn_t, aggr_dis,  N_DIS);
  aggregate<0><<<(N_DRUG + 3) / 4, 256, 0, stream>>>(Xs_r, Xd_r, si_r, sorted_r, offs_drug, cnt_drug, nullptr, attn_r, aggr_drug, N_DRUG);

  // 2 output linears, persistent per-segment blocks (tiles 782/313)
  Seg od;
  od.A[0] = aggr_drug; od.W[0] = Wo_drug; od.bias[0] = bo_drug; od.out[0] = out_drug; od.M[0] = N_DRUG;
  od.A[1] = aggr_dis;  od.W[1] = Wo_dis;  od.bias[1] = bo_dis;  od.out[1] = out_dis;  od.M[1] = N_DIS;
  od.A[2] = od.A[1];   od.W[2] = od.W[1]; od.bias[2] = od.bias[1]; od.out[2] = od.out[1]; od.M[2] = N_DIS;
  od.A[3] = od.A[1];   od.W[3] = od.W[1]; od.bias[3] = od.bias[1]; od.out[3] = od.out[1]; od.M[3] = N_DIS;
  od.bstart[0] = 0; od.bstart[1] = 548; od.bstart[2] = 768; od.bstart[3] = 768; od.bstart[4] = 768;
  gemm_seg<1, 0><<<768, 256, 0, stream>>>(od);
}

// Round 6
// 382.069 us; speedup vs baseline: 3.1320x; 1.0615x over previous
//
#include <hip/hip_runtime.h>
#include <hip/hip_bf16.h>
#include <math.h>

#define N_DRUG 50000
#define N_DIS  20000
#define NE     250000
#define NE_PAD 250048   // 3907 full 64-row tiles (gate stored without bounds checks)

// scan geometry: segment 0 = cnt_dis (20000), segment 1 = cnt_drug (50000)
#define NB0 79     // ceil(20000/256)
#define NBT 275    // NB0 + ceil(50000/256)

typedef __bf16 bf16x8 __attribute__((ext_vector_type(8)));
typedef __bf16 bf16x4 __attribute__((ext_vector_type(4)));
typedef __bf16 bf16x2 __attribute__((ext_vector_type(2)));
typedef float  f32x4  __attribute__((ext_vector_type(4)));
typedef float  f32x2  __attribute__((ext_vector_type(2)));

__device__ __forceinline__ bf16x8 bz8() {
  bf16x8 v;
  #pragma unroll
  for (int j = 0; j < 8; ++j) v[j] = (__bf16)0.f;
  return v;
}

// Fast gelu: erf via Abramowitz-Stegun 7.1.27 (|erf err| <= 5e-4), 1/sqrt(2)
// folded into coefficients. gelu(x)=0.5*x*(2-p^-4) for x>=0, 0.5*x*p^-4 else.
__device__ __forceinline__ float gelu_fast(float x) {
  float ax = fabsf(x);
  float t = fmaf(ax, 0.019527f, 3.43654e-4f);
  t = fmaf(ax, t, 0.1151945f);
  t = fmaf(ax, t, 0.1968564f);
  float p = fmaf(ax, t, 1.0f);
  float p2 = p * p;
  float p4 = p2 * p2;
  float r = __builtin_amdgcn_rcpf(p4);
  float sel = (x >= 0.f) ? (2.0f - r) : r;
  return 0.5f * x * sel;
}

__device__ __forceinline__ float sigmoid_fast(float v) {
  return __builtin_amdgcn_rcpf(1.0f + __expf(-v));
}

// ---------------------------------------------------------------------------
// Persistent multi-segment [M,128] @ [128,128] GEMM.
// Per-segment block partition (bstart[5]); each block stages its segment's W
// to LDS ONCE, then grid-strides tiles. A-fragments load directly from global
// into registers, software-pipelined one tile ahead (no barriers in the loop,
// so the in-flight loads overlap the MFMAs + stores of the current tile).
// ---------------------------------------------------------------------------
struct Seg {
  const void* A[4];
  const float* W[4];
  const float* bias[4];
  void* out[4];
  int M[4];
  int bstart[5];
};

template <int AIN_BF16, int OUT_BF16>
__global__ __launch_bounds__(256)
void gemm_seg(Seg d)
{
  __shared__ __bf16 Wt[128][136];   // W transposed: Wt[n][k]

  const int b = blockIdx.x;
  const int sidx = (b >= d.bstart[3]) ? 3 : (b >= d.bstart[2]) ? 2
                 : (b >= d.bstart[1]) ? 1 : 0;
  const int nb = d.bstart[sidx + 1] - d.bstart[sidx];
  const int lb = b - d.bstart[sidx];
  const float* W = d.W[sidx];
  const float* bias = d.bias[sidx];
  const int M = d.M[sidx];
  const int ntiles = (M + 63) >> 6;
  const int tid = threadIdx.x;
  const int wv = tid >> 6, lane = tid & 63;
  const int m16 = lane & 15, quad = lane >> 4;

  for (int idx = tid; idx < 16384; idx += 256) {
    int k = idx >> 7, n = idx & 127;
    Wt[n][k] = (__bf16)W[idx];
  }
  __syncthreads();   // the only barrier: Wt visible to all waves

  float bv[8];
  #pragma unroll
  for (int ct = 0; ct < 8; ++ct) bv[ct] = bias[ct * 16 + m16];

  // tile A-fragment loader (guarded for t beyond range / rows beyond M)
  auto load_afr = [&](int t, bf16x8* afr) {
    const int arow = (t << 6) + wv * 16 + m16;
    const bool ok = (t < ntiles) && (arow < M);
    if (AIN_BF16) {
      const __bf16* ap = (const __bf16*)d.A[sidx] + (long)arow * 128 + quad * 8;
      #pragma unroll
      for (int kt = 0; kt < 4; ++kt)
        afr[kt] = ok ? *(const bf16x8*)(ap + kt * 32) : bz8();
    } else {
      const float* ap = (const float*)d.A[sidx] + (long)arow * 128 + quad * 8;
      #pragma unroll
      for (int kt = 0; kt < 4; ++kt) {
        bf16x8 v = bz8();
        if (ok) {
          f32x4 lo = *(const f32x4*)(ap + kt * 32);
          f32x4 hi = *(const f32x4*)(ap + kt * 32 + 4);
          #pragma unroll
          for (int j = 0; j < 4; ++j) { v[j] = (__bf16)lo[j]; v[4 + j] = (__bf16)hi[j]; }
        }
        afr[kt] = v;
      }
    }
  };

  bf16x8 afr[4];
  if (lb < ntiles) load_afr(lb, afr);

  for (int t = lb; t < ntiles; t += nb) {
    bf16x8 nafr[4];
    load_afr(t + nb, nafr);   // in flight during this tile's MFMA + stores

    f32x4 acc[8];
    #pragma unroll
    for (int ct = 0; ct < 8; ++ct) acc[ct] = (f32x4){0.f, 0.f, 0.f, 0.f};
    #pragma unroll
    for (int kt = 0; kt < 4; ++kt) {
      #pragma unroll
      for (int ct = 0; ct < 8; ++ct) {
        bf16x8 bfr = *(const bf16x8*)&Wt[ct * 16 + m16][kt * 32 + quad * 8];
        acc[ct] = __builtin_amdgcn_mfma_f32_16x16x32_bf16(afr[kt], bfr, acc[ct], 0, 0, 0);
      }
    }

    // C/D layout: col=lane&15, row=quad*4+reg
    const int rb = (t << 6) + wv * 16 + quad * 4;
    #pragma unroll
    for (int ct = 0; ct < 8; ++ct) {
      const int col = ct * 16 + m16;
      #pragma unroll
      for (int rg = 0; rg < 4; ++rg) {
        int gr = rb + rg;
        if (gr < M) {
          float v = acc[ct][rg] + bv[ct];
          if (OUT_BF16) ((__bf16*)d.out[sidx])[(long)gr * 128 + col] = (__bf16)v;
          else          ((float*)d.out[sidx])[(long)gr * 128 + col] = v;
        }
      }
    }
    #pragma unroll
    for (int kt = 0; kt < 4; ++kt) afr[kt] = nafr[kt];
  }
}

// ---------------------------------------------------------------------------
// Edge gate: out = sigmoid( gelu(ea@Wg1+bg1) @ W2 + bg2 ), bf16 out.
// Persistent blocks; W2 staged to LDS once. Layer-1 is a zero-padded-K MFMA
// (quad-0 lanes carry the 8 real ea values). gelu applied in C-layout, the
// wave-private LDS stripe H (rows [wv*16,wv*16+16)) does both relayouts:
//   C-layout -> A-frag (hidden into layer-2) and C-layout -> row-major
// (sigmoid out), so global stores are 4 fully-coalesced b128s per lane.
// gate buffer is padded to NE_PAD rows: NO bounds checks anywhere.
// ---------------------------------------------------------------------------
__global__ __launch_bounds__(256)
void gate_kernel(const float* __restrict__ EA, const float* __restrict__ W2,
                 const float* __restrict__ Wg1, const float* __restrict__ bg1,
                 const float* __restrict__ bg2, __bf16* __restrict__ out)
{
  __shared__ __bf16 Wt[128][136];
  __shared__ __bf16 H[64][136];
  const int tid = threadIdx.x;
  const int wv = tid >> 6, lane = tid & 63;
  const int m16 = lane & 15, quad = lane >> 4;

  for (int idx = tid; idx < 16384; idx += 256) {
    int k = idx >> 7, n = idx & 127;
    Wt[n][k] = (__bf16)W2[idx];
  }
  __syncthreads();

  // layer-1 B-fragments: B[n=ct*16+m16][k=quad*8+j] = Wg1[k][n], k<8 real
  bf16x8 b1[8];
  #pragma unroll
  for (int ct = 0; ct < 8; ++ct) {
    bf16x8 v = bz8();
    if (quad == 0) {
      #pragma unroll
      for (int j = 0; j < 8; ++j) v[j] = (__bf16)Wg1[j * 128 + ct * 16 + m16];
    }
    b1[ct] = v;
  }
  float b1v[8], b2v[8];
  #pragma unroll
  for (int ct = 0; ct < 8; ++ct) {
    b1v[ct] = bg1[ct * 16 + m16];
    b2v[ct] = bg2[ct * 16 + m16];
  }

  const int ntiles = (NE + 63) >> 6;   // 3907
  const int hr = wv * 16 + quad * 4;   // C-layout row base in H stripe
  const int ar = wv * 16 + m16;        // A-frag / row-major row in H stripe

  for (int t = blockIdx.x; t < ntiles; t += gridDim.x) {
    const int r0 = t << 6;
    const int arow = r0 + wv * 16 + m16;

    // layer-1 A-frag: quad 0 holds the ea row (k=0..7), rest zero
    bf16x8 a1 = bz8();
    if (quad == 0 && arow < NE) {
      f32x4 e0 = *(const f32x4*)(EA + (long)arow * 8);
      f32x4 e1 = *(const f32x4*)(EA + (long)arow * 8 + 4);
      #pragma unroll
      for (int j = 0; j < 4; ++j) { a1[j] = (__bf16)e0[j]; a1[4 + j] = (__bf16)e1[j]; }
    }
    f32x4 h[8];
    #pragma unroll
    for (int ct = 0; ct < 8; ++ct)
      h[ct] = __builtin_amdgcn_mfma_f32_16x16x32_bf16(a1, b1[ct], (f32x4){0.f,0.f,0.f,0.f}, 0, 0, 0);

    // bias + gelu in C-layout -> wave-private H stripe (in-order DS pipe)
    #pragma unroll
    for (int ct = 0; ct < 8; ++ct) {
      const int col = ct * 16 + m16;
      #pragma unroll
      for (int rg = 0; rg < 4; ++rg)
        H[hr + rg][col] = (__bf16)gelu_fast(h[ct][rg] + b1v[ct]);
    }
    asm volatile("s_waitcnt lgkmcnt(0)" ::: "memory");

    bf16x8 afr[4];
    #pragma unroll
    for (int kt = 0; kt < 4; ++kt)
      afr[kt] = *(const bf16x8*)&H[ar][kt * 32 + quad * 8];
    asm volatile("" ::: "memory");

    f32x4 acc[8];
    #pragma unroll
    for (int ct = 0; ct < 8; ++ct) acc[ct] = (f32x4){0.f, 0.f, 0.f, 0.f};
    #pragma unroll
    for (int kt = 0; kt < 4; ++kt) {
      #pragma unroll
      for (int ct = 0; ct < 8; ++ct) {
        bf16x8 bfr = *(const bf16x8*)&Wt[ct * 16 + m16][kt * 32 + quad * 8];
        acc[ct] = __builtin_amdgcn_mfma_f32_16x16x32_bf16(afr[kt], bfr, acc[ct], 0, 0, 0);
      }
    }

    // sigmoid in C-layout -> H stripe again (safe: in-order per-wave DS)
    #pragma unroll
    for (int ct = 0; ct < 8; ++ct) {
      const int col = ct * 16 + m16;
      #pragma unroll
      for (int rg = 0; rg < 4; ++rg)
        H[hr + rg][col] = (__bf16)sigmoid_fast(acc[ct][rg] + b2v[ct]);
    }
    asm volatile("s_waitcnt lgkmcnt(0)" ::: "memory");

    // row-major readout + coalesced b128 stores (16 full cachelines/inst)
    bf16x8 gout[4];
    #pragma unroll
    for (int kt = 0; kt < 4; ++kt)
      gout[kt] = *(const bf16x8*)&H[ar][kt * 32 + quad * 8];
    asm volatile("" ::: "memory");

    __bf16* op = out + (long)arow * 128 + quad * 8;
    #pragma unroll
    for (int kt = 0; kt < 4; ++kt)
      *(bf16x8*)(op + kt * 32) = gout[kt];
  }
}

// ---------------------------------------------------------------------------
// Counting sort of edges by destination node (both edge types per launch).
// ---------------------------------------------------------------------------
__global__ __launch_bounds__(256)
void histo2(const int* __restrict__ di_t, const int* __restrict__ di_r,
            int* __restrict__ cnt_dis, int* __restrict__ cnt_drug, int half) {
  int b = blockIdx.x;
  if (b < half) {
    int i = b * 256 + threadIdx.x;
    if (i < NE) atomicAdd(&cnt_dis[di_t[i]], 1);
  } else {
    int i = (b - half) * 256 + threadIdx.x;
    if (i < NE) atomicAdd(&cnt_drug[di_r[i]], 1);
  }
}

__global__ __launch_bounds__(256)
void scatter2(const int* __restrict__ di_t, const int* __restrict__ di_r,
              int* __restrict__ cur_dis, int* __restrict__ cur_drug,
              int* __restrict__ sorted_t, int* __restrict__ sorted_r, int half) {
  int b = blockIdx.x;
  if (b < half) {
    int i = b * 256 + threadIdx.x;
    if (i < NE) sorted_t[atomicAdd(&cur_dis[di_t[i]], 1)] = i;
  } else {
    int i = (b - half) * 256 + threadIdx.x;
    if (i < NE) sorted_r[atomicAdd(&cur_drug[di_r[i]], 1)] = i;
  }
}

// ---------------------------------------------------------------------------
// Device-wide segmented exclusive scan over concatenated cnt_dis||cnt_drug.
// ---------------------------------------------------------------------------
__device__ __forceinline__ void seg_geom(int b, int& base, int& n, int& lb) {
  if (b < NB0) { base = 0;     n = 20000; lb = b; }
  else         { base = 20000; n = 50000; lb = b - NB0; }
}

__global__ __launch_bounds__(256)
void scan_partial(const int* __restrict__ cnt, int* __restrict__ bsum) {
  __shared__ int sh[256];
  int b = blockIdx.x, t = threadIdx.x;
  int base, n, lb; seg_geom(b, base, n, lb);
  int i = lb * 256 + t;
  sh[t] = (i < n) ? cnt[base + i] : 0;
  __syncthreads();
  for (int d = 1; d < 256; d <<= 1) {
    int vv = (t >= d) ? sh[t - d] : 0;
    __syncthreads();
    sh[t] += vv;
    __syncthreads();
  }
  if (t == 255) bsum[b] = sh[255];
}

__global__ __launch_bounds__(512)
void scan_block(const int* __restrict__ bsum, int* __restrict__ bexc) {
  __shared__ int v[512];
  __shared__ int f[512];
  int t = threadIdx.x;
  int own = (t < NBT) ? bsum[t] : 0;
  v[t] = own;
  f[t] = (t == 0 || t == NB0 || t >= NBT) ? 1 : 0;
  __syncthreads();
  for (int d = 1; d < 512; d <<= 1) {
    int vv = 0, ff = 1;
    if (t >= d) { vv = v[t - d]; ff = f[t - d]; }
    __syncthreads();
    if (t >= d && !f[t]) { v[t] += vv; f[t] |= ff; }
    __syncthreads();
  }
  if (t < NBT) bexc[t] = v[t] - own;   // exclusive within segment
}

__global__ __launch_bounds__(256)
void scan_final(const int* __restrict__ cnt, const int* __restrict__ bexc,
                int* __restrict__ offs, int* __restrict__ cursor) {
  __shared__ int sh[256];
  int b = blockIdx.x, t = threadIdx.x;
  int base, n, lb; seg_geom(b, base, n, lb);
  int i = lb * 256 + t;
  int own = (i < n) ? cnt[base + i] : 0;
  sh[t] = own;
  __syncthreads();
  for (int d = 1; d < 256; d <<= 1) {
    int vv = (t >= d) ? sh[t - d] : 0;
    __syncthreads();
    sh[t] += vv;
    __syncthreads();
  }
  int off = bexc[b] + sh[t] - own;
  if (i < n) { offs[base + i] = off; cursor[base + i] = off; }
}

// ---------------------------------------------------------------------------
// Gather-side aggregation: one 64-lane wave per destination node; lane owns
// channels {2*lane, 2*lane+1}. Data (xs, gate) software-pipelined one edge
// ahead along with the index chain. Softmax normalization fused in epilogue.
// ---------------------------------------------------------------------------
template <int HASGATE>
__global__ __launch_bounds__(256)
void aggregate(const __bf16* __restrict__ Xs, const __bf16* __restrict__ Xd,
               const int* __restrict__ si, const int* __restrict__ sorted,
               const int* __restrict__ offs, const int* __restrict__ cnt,
               const __bf16* __restrict__ gate, const float* __restrict__ attn,
               __bf16* __restrict__ out, int n)
{
  int w = (int)((blockIdx.x * 256 + threadIdx.x) >> 6);
  if (w >= n) return;
  const int lane = threadIdx.x & 63;
  const int c = lane * 2;

  f32x2 at = *(const f32x2*)(attn + c);
  bf16x2 xdb = *(const bf16x2*)(Xd + (long)w * 128 + c);
  const float xd0 = (float)xdb[0], xd1 = (float)xdb[1];
  const int start = offs[w];
  const int m = cnt[w];

  float n0 = 0.f, n1 = 0.f, den = 0.f;

  bf16x2 xs_n = {(__bf16)0.f, (__bf16)0.f};
  bf16x2 g_n  = {(__bf16)0.f, (__bf16)0.f};
  if (m > 0) {
    int e = sorted[start];
    int s = si[e];
    xs_n = *(const bf16x2*)(Xs + (long)s * 128 + c);
    if (HASGATE) g_n = *(const bf16x2*)(gate + (long)e * 128 + c);
  }
  for (int j = 0; j < m; ++j) {
    bf16x2 xsb = xs_n, gb = g_n;
    if (j + 1 < m) {
      int e = sorted[start + j + 1];
      int s = si[e];
      xs_n = *(const bf16x2*)(Xs + (long)s * 128 + c);
      if (HASGATE) g_n = *(const bf16x2*)(gate + (long)e * 128 + c);
    }
    float xs0 = (float)xsb[0], xs1 = (float)xsb[1];
    float m0 = xs0 + xd0, m1 = xs1 + xd1;
    if (HASGATE) { m0 *= (float)gb[0]; m1 *= (float)gb[1]; }
    float part = (xs0 * xd0 + xs1 * xd1) * 0.17677669529663687f
               + m0 * at[0] + m1 * at[1];
    part += __shfl_xor(part, 1);
    part += __shfl_xor(part, 2);
    part += __shfl_xor(part, 4);
    part += __shfl_xor(part, 8);
    float ex = __expf(part);
    n0 += m0 * ex;
    n1 += m1 * ex;
    den += ex;
  }

  float r = __builtin_amdgcn_rcpf(den + 1e-16f);
  bf16x2 o;
  o[0] = (__bf16)(n0 * r);
  o[1] = (__bf16)(n1 * r);
  *(bf16x2*)(out + (long)w * 128 + c) = o;
}

// ---------------------------------------------------------------------------
extern "C" void kernel_launch(void* const* d_in, const int* in_sizes, int n_in,
                              void* d_out, int out_size, void* d_ws, size_t ws_size,
                              hipStream_t stream)
{
  const float* x_drug  = (const float*)d_in[0];
  const float* x_dis   = (const float*)d_in[1];
  const float* ea      = (const float*)d_in[2];
  const int*   si_t    = (const int*)d_in[3];
  const int*   di_t    = (const int*)d_in[4];
  const int*   si_r    = (const int*)d_in[5];
  const int*   di_r    = (const int*)d_in[6];
  const float* Ws_t    = (const float*)d_in[7];
  const float* bs_t    = (const float*)d_in[8];
  const float* Wd_t    = (const float*)d_in[9];
  const float* bd_t    = (const float*)d_in[10];
  const float* attn_t  = (const float*)d_in[11];
  const float* Wg1     = (const float*)d_in[12];
  const float* bg1     = (const float*)d_in[13];
  const float* Wg2     = (const float*)d_in[14];
  const float* bg2     = (const float*)d_in[15];
  const float* Ws_r    = (const float*)d_in[16];
  const float* bs_r    = (const float*)d_in[17];
  const float* Wd_r    = (const float*)d_in[18];
  const float* bd_r    = (const float*)d_in[19];
  const float* attn_r  = (const float*)d_in[20];
  const float* Wo_drug = (const float*)d_in[21];
  const float* bo_drug = (const float*)d_in[22];
  const float* Wo_dis  = (const float*)d_in[23];
  const float* bo_dis  = (const float*)d_in[24];

  // workspace layout (~108 MB); X/aggr/gate tensors bf16
  __bf16* wsb      = (__bf16*)d_ws;
  __bf16* Xs_t     = wsb;                  // 50000*128 (reused as aggr_drug)
  __bf16* Xd_t     = Xs_t + 6400000;       // 20000*128
  __bf16* Xs_r     = Xd_t + 2560000;       // 20000*128
  __bf16* Xd_r     = Xs_r + 2560000;       // 50000*128
  __bf16* aggr_dis = Xd_r + 6400000;       // 20000*128
  __bf16* gate     = aggr_dis + 2560000;   // NE_PAD*128 (padded tiles)
  int* cnt_dis    = (int*)(gate + (long)NE_PAD * 128);  // 20000  --+ contiguous:
  int* cnt_drug   = cnt_dis + 20000;       // 50000             | zeroed+scanned
  int* offs_dis   = cnt_drug + 50000;      // 20000             | as one region
  int* offs_drug  = offs_dis + 20000;      // 50000             |
  int* cur_dis    = offs_drug + 50000;     // 20000             |
  int* cur_drug   = cur_dis + 20000;       // 50000           --+
  int* sorted_t   = cur_drug + 50000;      // 250000
  int* sorted_r   = sorted_t + 250000;     // 250000
  int* bsum       = sorted_r + 250000;     // 275
  int* bexc       = bsum + 512;            // 275

  __bf16* aggr_drug = Xs_t;                // safe: Xs_t dead after treats agg

  float* out_drug = (float*)d_out;
  float* out_dis  = out_drug + (long)N_DRUG * 128;

  hipMemsetAsync(cnt_dis, 0, 70000 * sizeof(int), stream);

  const int eb = (NE + 255) / 256;         // 977

  // counting sort by destination (both convs), device-wide 3-phase scan
  histo2<<<2 * eb, 256, 0, stream>>>(di_t, di_r, cnt_dis, cnt_drug, eb);
  scan_partial<<<NBT, 256, 0, stream>>>(cnt_dis, bsum);
  scan_block<<<1, 512, 0, stream>>>(bsum, bexc);
  scan_final<<<NBT, 256, 0, stream>>>(cnt_dis, bexc, offs_dis, cur_dis);
  scatter2<<<2 * eb, 256, 0, stream>>>(di_t, di_r, cur_dis, cur_drug, sorted_t, sorted_r, eb);

  // 4 node transforms, persistent per-segment blocks (tiles 782/313/313/782)
  Seg nd;
  nd.A[0] = x_drug; nd.W[0] = Ws_t; nd.bias[0] = bs_t; nd.out[0] = Xs_t; nd.M[0] = N_DRUG;
  nd.A[1] = x_dis;  nd.W[1] = Wd_t; nd.bias[1] = bd_t; nd.out[1] = Xd_t; nd.M[1] = N_DIS;
  nd.A[2] = x_dis;  nd.W[2] = Ws_r; nd.bias[2] = bs_r; nd.out[2] = Xs_r; nd.M[2] = N_DIS;
  nd.A[3] = x_drug; nd.W[3] = Wd_r; nd.bias[3] = bd_r; nd.out[3] = Xd_r; nd.M[3] = N_DRUG;
  nd.bstart[0] = 0; nd.bstart[1] = 274; nd.bstart[2] = 384; nd.bstart[3] = 494; nd.bstart[4] = 768;
  gemm_seg<0, 1><<<768, 256, 0, stream>>>(nd);

  // edge gate, persistent blocks (512 = 2 blocks/CU exactly, no tail)
  gate_kernel<<<512, 256, 0, stream>>>(ea, Wg2, Wg1, bg1, bg2, gate);

  // gather-side aggregation, one wave per destination node (no atomics)
  aggregate<1><<<(N_DIS + 3) / 4,  256, 0, stream>>>(Xs_t, Xd_t, si_t, sorted_t, offs_dis,  cnt_dis,  gate,    attn_t, aggr_dis,  N_DIS);
  aggregate<0><<<(N_DRUG + 3) / 4, 256, 0, stream>>>(Xs_r, Xd_r, si_r, sorted_r, offs_drug, cnt_drug, nullptr, attn_r, aggr_drug, N_DRUG);

  // 2 output linears, persistent per-segment blocks (tiles 782/313)
  Seg od;
  od.A[0] = aggr_drug; od.W[0] = Wo_drug; od.bias[0] = bo_drug; od.out[0] = out_drug; od.M[0] = N_DRUG;
  od.A[1] = aggr_dis;  od.W[1] = Wo_dis;  od.bias[1] = bo_dis;  od.out[1] = out_dis;  od.M[1] = N_DIS;
  od.A[2] = od.A[1];   od.W[2] = od.W[1]; od.bias[2] = od.bias[1]; od.out[2] = od.out[1]; od.M[2] = N_DIS;
  od.A[3] = od.A[1];   od.W[3] = od.W[1]; od.bias[3] = od.bias[1]; od.out[3] = od.out[1]; od.M[3] = N_DIS;
  od.bstart[0] = 0; od.bstart[1] = 548; od.bstart[2] = 768; od.bstart[3] = 768; od.bstart[4] = 768;
  gemm_seg<1, 0><<<768, 256, 0, stream>>>(od);
}

// Round 7
// 339.489 us; speedup vs baseline: 3.5248x; 1.1254x over previous
//
#include <hip/hip_runtime.h>
#include <hip/hip_bf16.h>
#include <math.h>

#define N_DRUG 50000
#define N_DIS  20000
#define NE     250000
#define NE_PAD 250048   // 3907 full 64-row tiles (gate stored without bounds checks)

// scan geometry: segment 0 = cnt_dis (20000), segment 1 = cnt_drug (50000)
#define NB0 79     // ceil(20000/256)
#define NBT 275    // NB0 + ceil(50000/256)

typedef __bf16 bf16x8 __attribute__((ext_vector_type(8)));
typedef __bf16 bf16x4 __attribute__((ext_vector_type(4)));
typedef __bf16 bf16x2 __attribute__((ext_vector_type(2)));
typedef float  f32x4  __attribute__((ext_vector_type(4)));
typedef float  f32x2  __attribute__((ext_vector_type(2)));

__device__ __forceinline__ bf16x8 bz8() {
  bf16x8 v;
  #pragma unroll
  for (int j = 0; j < 8; ++j) v[j] = (__bf16)0.f;
  return v;
}

// Fast gelu: erf via Abramowitz-Stegun 7.1.27 (|erf err| <= 5e-4), 1/sqrt(2)
// folded into coefficients. gelu(x)=0.5*x*(2-p^-4) for x>=0, 0.5*x*p^-4 else.
__device__ __forceinline__ float gelu_fast(float x) {
  float ax = fabsf(x);
  float t = fmaf(ax, 0.019527f, 3.43654e-4f);
  t = fmaf(ax, t, 0.1151945f);
  t = fmaf(ax, t, 0.1968564f);
  float p = fmaf(ax, t, 1.0f);
  float p2 = p * p;
  float p4 = p2 * p2;
  float r = __builtin_amdgcn_rcpf(p4);
  float sel = (x >= 0.f) ? (2.0f - r) : r;
  return 0.5f * x * sel;
}

__device__ __forceinline__ float sigmoid_fast(float v) {
  return __builtin_amdgcn_rcpf(1.0f + __expf(-v));
}

// ---------------------------------------------------------------------------
// Persistent multi-segment [M,128] @ [128,128] GEMM.
// Per-segment block partition (bstart[5]); each block stages its segment's W
// to LDS ONCE, then grid-strides tiles. A-fragments load directly from global
// into registers, software-pipelined one tile ahead (no barriers in the loop).
// ---------------------------------------------------------------------------
struct Seg {
  const void* A[4];
  const float* W[4];
  const float* bias[4];
  void* out[4];
  int M[4];
  int bstart[5];
};

template <int AIN_BF16, int OUT_BF16>
__global__ __launch_bounds__(256)
void gemm_seg(Seg d)
{
  __shared__ __bf16 Wt[128][136];   // W transposed: Wt[n][k]

  const int b = blockIdx.x;
  const int sidx = (b >= d.bstart[3]) ? 3 : (b >= d.bstart[2]) ? 2
                 : (b >= d.bstart[1]) ? 1 : 0;
  const int nb = d.bstart[sidx + 1] - d.bstart[sidx];
  const int lb = b - d.bstart[sidx];
  const float* W = d.W[sidx];
  const float* bias = d.bias[sidx];
  const int M = d.M[sidx];
  const int ntiles = (M + 63) >> 6;
  const int tid = threadIdx.x;
  const int wv = tid >> 6, lane = tid & 63;
  const int m16 = lane & 15, quad = lane >> 4;

  for (int idx = tid; idx < 16384; idx += 256) {
    int k = idx >> 7, n = idx & 127;
    Wt[n][k] = (__bf16)W[idx];
  }
  __syncthreads();   // the only barrier: Wt visible to all waves

  float bv[8];
  #pragma unroll
  for (int ct = 0; ct < 8; ++ct) bv[ct] = bias[ct * 16 + m16];

  auto load_afr = [&](int t, bf16x8* afr) {
    const int arow = (t << 6) + wv * 16 + m16;
    const bool ok = (t < ntiles) && (arow < M);
    if (AIN_BF16) {
      const __bf16* ap = (const __bf16*)d.A[sidx] + (long)arow * 128 + quad * 8;
      #pragma unroll
      for (int kt = 0; kt < 4; ++kt)
        afr[kt] = ok ? *(const bf16x8*)(ap + kt * 32) : bz8();
    } else {
      const float* ap = (const float*)d.A[sidx] + (long)arow * 128 + quad * 8;
      #pragma unroll
      for (int kt = 0; kt < 4; ++kt) {
        bf16x8 v = bz8();
        if (ok) {
          f32x4 lo = *(const f32x4*)(ap + kt * 32);
          f32x4 hi = *(const f32x4*)(ap + kt * 32 + 4);
          #pragma unroll
          for (int j = 0; j < 4; ++j) { v[j] = (__bf16)lo[j]; v[4 + j] = (__bf16)hi[j]; }
        }
        afr[kt] = v;
      }
    }
  };

  bf16x8 afr[4];
  if (lb < ntiles) load_afr(lb, afr);

  for (int t = lb; t < ntiles; t += nb) {
    bf16x8 nafr[4];
    load_afr(t + nb, nafr);   // in flight during this tile's MFMA + stores

    f32x4 acc[8];
    #pragma unroll
    for (int ct = 0; ct < 8; ++ct) acc[ct] = (f32x4){0.f, 0.f, 0.f, 0.f};
    #pragma unroll
    for (int kt = 0; kt < 4; ++kt) {
      #pragma unroll
      for (int ct = 0; ct < 8; ++ct) {
        bf16x8 bfr = *(const bf16x8*)&Wt[ct * 16 + m16][kt * 32 + quad * 8];
        acc[ct] = __builtin_amdgcn_mfma_f32_16x16x32_bf16(afr[kt], bfr, acc[ct], 0, 0, 0);
      }
    }

    // C/D layout: col=lane&15, row=quad*4+reg
    const int rb = (t << 6) + wv * 16 + quad * 4;
    #pragma unroll
    for (int ct = 0; ct < 8; ++ct) {
      const int col = ct * 16 + m16;
      #pragma unroll
      for (int rg = 0; rg < 4; ++rg) {
        int gr = rb + rg;
        if (gr < M) {
          float v = acc[ct][rg] + bv[ct];
          if (OUT_BF16) ((__bf16*)d.out[sidx])[(long)gr * 128 + col] = (__bf16)v;
          else          ((float*)d.out[sidx])[(long)gr * 128 + col] = v;
        }
      }
    }
    #pragma unroll
    for (int kt = 0; kt < 4; ++kt) afr[kt] = nafr[kt];
  }
}

// ---------------------------------------------------------------------------
// Edge gate, SORTED ORDER: row p of `out` is the gate of edge sorted_t[p],
// so the aggregate reads it fully sequentially. ea rows gathered (32 B,
// hidden under MFMA + TLP). Otherwise identical to R6's gate kernel:
// zero-padded-K layer-1 MFMA, gelu in C-layout, wave-private LDS stripe H
// for both relayouts, coalesced b128 stores, no bounds checks on stores.
// ---------------------------------------------------------------------------
__global__ __launch_bounds__(256)
void gate_kernel(const float* __restrict__ EA, const float* __restrict__ W2,
                 const float* __restrict__ Wg1, const float* __restrict__ bg1,
                 const float* __restrict__ bg2, const int* __restrict__ sorted_t,
                 __bf16* __restrict__ out)
{
  __shared__ __bf16 Wt[128][136];
  __shared__ __bf16 H[64][136];
  const int tid = threadIdx.x;
  const int wv = tid >> 6, lane = tid & 63;
  const int m16 = lane & 15, quad = lane >> 4;

  for (int idx = tid; idx < 16384; idx += 256) {
    int k = idx >> 7, n = idx & 127;
    Wt[n][k] = (__bf16)W2[idx];
  }
  __syncthreads();

  // layer-1 B-fragments: B[n=ct*16+m16][k=quad*8+j] = Wg1[k][n], k<8 real
  bf16x8 b1[8];
  #pragma unroll
  for (int ct = 0; ct < 8; ++ct) {
    bf16x8 v = bz8();
    if (quad == 0) {
      #pragma unroll
      for (int j = 0; j < 8; ++j) v[j] = (__bf16)Wg1[j * 128 + ct * 16 + m16];
    }
    b1[ct] = v;
  }
  float b1v[8], b2v[8];
  #pragma unroll
  for (int ct = 0; ct < 8; ++ct) {
    b1v[ct] = bg1[ct * 16 + m16];
    b2v[ct] = bg2[ct * 16 + m16];
  }

  const int ntiles = (NE + 63) >> 6;   // 3907
  const int hr = wv * 16 + quad * 4;   // C-layout row base in H stripe
  const int ar = wv * 16 + m16;        // A-frag / row-major row in H stripe

  for (int t = blockIdx.x; t < ntiles; t += gridDim.x) {
    const int p = (t << 6) + wv * 16 + m16;   // sorted position == out row

    // layer-1 A-frag: quad 0 holds the gathered ea row (k=0..7), rest zero
    bf16x8 a1 = bz8();
    if (quad == 0 && p < NE) {
      int e = sorted_t[p];
      f32x4 e0 = *(const f32x4*)(EA + (long)e * 8);
      f32x4 e1 = *(const f32x4*)(EA + (long)e * 8 + 4);
      #pragma unroll
      for (int j = 0; j < 4; ++j) { a1[j] = (__bf16)e0[j]; a1[4 + j] = (__bf16)e1[j]; }
    }
    f32x4 h[8];
    #pragma unroll
    for (int ct = 0; ct < 8; ++ct)
      h[ct] = __builtin_amdgcn_mfma_f32_16x16x32_bf16(a1, b1[ct], (f32x4){0.f,0.f,0.f,0.f}, 0, 0, 0);

    // bias + gelu in C-layout -> wave-private H stripe (in-order DS pipe)
    #pragma unroll
    for (int ct = 0; ct < 8; ++ct) {
      const int col = ct * 16 + m16;
      #pragma unroll
      for (int rg = 0; rg < 4; ++rg)
        H[hr + rg][col] = (__bf16)gelu_fast(h[ct][rg] + b1v[ct]);
    }
    asm volatile("s_waitcnt lgkmcnt(0)" ::: "memory");

    bf16x8 afr[4];
    #pragma unroll
    for (int kt = 0; kt < 4; ++kt)
      afr[kt] = *(const bf16x8*)&H[ar][kt * 32 + quad * 8];
    asm volatile("" ::: "memory");

    f32x4 acc[8];
    #pragma unroll
    for (int ct = 0; ct < 8; ++ct) acc[ct] = (f32x4){0.f, 0.f, 0.f, 0.f};
    #pragma unroll
    for (int kt = 0; kt < 4; ++kt) {
      #pragma unroll
      for (int ct = 0; ct < 8; ++ct) {
        bf16x8 bfr = *(const bf16x8*)&Wt[ct * 16 + m16][kt * 32 + quad * 8];
        acc[ct] = __builtin_amdgcn_mfma_f32_16x16x32_bf16(afr[kt], bfr, acc[ct], 0, 0, 0);
      }
    }

    // sigmoid in C-layout -> H stripe again (safe: in-order per-wave DS)
    #pragma unroll
    for (int ct = 0; ct < 8; ++ct) {
      const int col = ct * 16 + m16;
      #pragma unroll
      for (int rg = 0; rg < 4; ++rg)
        H[hr + rg][col] = (__bf16)sigmoid_fast(acc[ct][rg] + b2v[ct]);
    }
    asm volatile("s_waitcnt lgkmcnt(0)" ::: "memory");

    bf16x8 gout[4];
    #pragma unroll
    for (int kt = 0; kt < 4; ++kt)
      gout[kt] = *(const bf16x8*)&H[ar][kt * 32 + quad * 8];
    asm volatile("" ::: "memory");

    __bf16* op = out + (long)p * 128 + quad * 8;
    #pragma unroll
    for (int kt = 0; kt < 4; ++kt)
      *(bf16x8*)(op + kt * 32) = gout[kt];
  }
}

// ---------------------------------------------------------------------------
// Counting sort of edges by destination node (both edge types per launch).
// scatter2 also materializes ssrc[p] = si[sorted[p]] (drops a dependency
// level in the aggregate; sorted_r itself is no longer needed).
// ---------------------------------------------------------------------------
__global__ __launch_bounds__(256)
void histo2(const int* __restrict__ di_t, const int* __restrict__ di_r,
            int* __restrict__ cnt_dis, int* __restrict__ cnt_drug, int half) {
  int b = blockIdx.x;
  if (b < half) {
    int i = b * 256 + threadIdx.x;
    if (i < NE) atomicAdd(&cnt_dis[di_t[i]], 1);
  } else {
    int i = (b - half) * 256 + threadIdx.x;
    if (i < NE) atomicAdd(&cnt_drug[di_r[i]], 1);
  }
}

__global__ __launch_bounds__(256)
void scatter2(const int* __restrict__ di_t, const int* __restrict__ di_r,
              const int* __restrict__ si_t, const int* __restrict__ si_r,
              int* __restrict__ cur_dis, int* __restrict__ cur_drug,
              int* __restrict__ sorted_t, int* __restrict__ ssrc_t,
              int* __restrict__ ssrc_r, int half) {
  int b = blockIdx.x;
  if (b < half) {
    int i = b * 256 + threadIdx.x;
    if (i < NE) {
      int p = atomicAdd(&cur_dis[di_t[i]], 1);
      sorted_t[p] = i;
      ssrc_t[p] = si_t[i];
    }
  } else {
    int i = (b - half) * 256 + threadIdx.x;
    if (i < NE) {
      int p = atomicAdd(&cur_drug[di_r[i]], 1);
      ssrc_r[p] = si_r[i];
    }
  }
}

// ---------------------------------------------------------------------------
// Device-wide segmented exclusive scan over concatenated cnt_dis||cnt_drug.
// ---------------------------------------------------------------------------
__device__ __forceinline__ void seg_geom(int b, int& base, int& n, int& lb) {
  if (b < NB0) { base = 0;     n = 20000; lb = b; }
  else         { base = 20000; n = 50000; lb = b - NB0; }
}

__global__ __launch_bounds__(256)
void scan_partial(const int* __restrict__ cnt, int* __restrict__ bsum) {
  __shared__ int sh[256];
  int b = blockIdx.x, t = threadIdx.x;
  int base, n, lb; seg_geom(b, base, n, lb);
  int i = lb * 256 + t;
  sh[t] = (i < n) ? cnt[base + i] : 0;
  __syncthreads();
  for (int d = 1; d < 256; d <<= 1) {
    int vv = (t >= d) ? sh[t - d] : 0;
    __syncthreads();
    sh[t] += vv;
    __syncthreads();
  }
  if (t == 255) bsum[b] = sh[255];
}

__global__ __launch_bounds__(512)
void scan_block(const int* __restrict__ bsum, int* __restrict__ bexc) {
  __shared__ int v[512];
  __shared__ int f[512];
  int t = threadIdx.x;
  int own = (t < NBT) ? bsum[t] : 0;
  v[t] = own;
  f[t] = (t == 0 || t == NB0 || t >= NBT) ? 1 : 0;
  __syncthreads();
  for (int d = 1; d < 512; d <<= 1) {
    int vv = 0, ff = 1;
    if (t >= d) { vv = v[t - d]; ff = f[t - d]; }
    __syncthreads();
    if (t >= d && !f[t]) { v[t] += vv; f[t] |= ff; }
    __syncthreads();
  }
  if (t < NBT) bexc[t] = v[t] - own;   // exclusive within segment
}

__global__ __launch_bounds__(256)
void scan_final(const int* __restrict__ cnt, const int* __restrict__ bexc,
                int* __restrict__ offs, int* __restrict__ cursor) {
  __shared__ int sh[256];
  int b = blockIdx.x, t = threadIdx.x;
  int base, n, lb; seg_geom(b, base, n, lb);
  int i = lb * 256 + t;
  int own = (i < n) ? cnt[base + i] : 0;
  sh[t] = own;
  __syncthreads();
  for (int d = 1; d < 256; d <<= 1) {
    int vv = (t >= d) ? sh[t - d] : 0;
    __syncthreads();
    sh[t] += vv;
    __syncthreads();
  }
  int off = bexc[b] + sh[t] - own;
  if (i < n) { offs[base + i] = off; cursor[base + i] = off; }
}

// ---------------------------------------------------------------------------
// Merged gather-side aggregation for BOTH convs: one 64-lane wave per
// destination node (gw < N_DIS -> treats/dis, else rev/drug); lane owns
// channels {2*lane, 2*lane+1}. Inner loop batches 4 edges, double-buffered
// (8 row-loads in flight), 4 independent shfl-reduction chains pipeline in
// the DS unit. ssrc is wave-uniform -> SMEM. gate reads are sequential rows
// (gate stored in sorted order). Output aliases Xd row-for-row: each node's
// xd row is read only by its own wave before being overwritten - safe.
// ---------------------------------------------------------------------------
__global__ __launch_bounds__(256)
void aggregate2(const __bf16* __restrict__ Xs_t, const __bf16* __restrict__ Xd_t,
                const __bf16* __restrict__ Xs_r, const __bf16* __restrict__ Xd_r,
                const int* __restrict__ ssrc_t, const int* __restrict__ ssrc_r,
                const int* __restrict__ offs, const int* __restrict__ cnt,
                const __bf16* __restrict__ gate_s,
                const float* __restrict__ attn_t, const float* __restrict__ attn_r,
                __bf16* __restrict__ aggr_dis, __bf16* __restrict__ aggr_drug)
{
  const int gw = (int)((blockIdx.x * 256 + threadIdx.x) >> 6);
  if (gw >= N_DIS + N_DRUG) return;
  const int lane = threadIdx.x & 63;
  const int c = lane * 2;
  const bool isDis = gw < N_DIS;
  const int node = isDis ? gw : gw - N_DIS;
  const __bf16* Xs = isDis ? Xs_t : Xs_r;
  const __bf16* Xd = isDis ? Xd_t : Xd_r;
  const int* ssrc = isDis ? ssrc_t : ssrc_r;
  const float* attn = isDis ? attn_t : attn_r;
  __bf16* outp = isDis ? aggr_dis : aggr_drug;

  f32x2 at = *(const f32x2*)(attn + c);
  bf16x2 xdb = *(const bf16x2*)(Xd + (long)node * 128 + c);
  const float xd0 = (float)xdb[0], xd1 = (float)xdb[1];
  const int start = offs[gw];
  const int m = cnt[gw];

  float n0 = 0.f, n1 = 0.f, den = 0.f;
  const bf16x2 z2 = {(__bf16)0.f, (__bf16)0.f};

  bf16x2 xa[4], ga[4];
  #pragma unroll
  for (int u = 0; u < 4; ++u) {
    xa[u] = z2; ga[u] = z2;
    if (u < m) {
      int s = ssrc[start + u];
      xa[u] = *(const bf16x2*)(Xs + (long)s * 128 + c);
      if (isDis) ga[u] = *(const bf16x2*)(gate_s + (long)(start + u) * 128 + c);
    }
  }

  for (int j = 0; j < m; j += 4) {
    bf16x2 xb[4], gb[4];
    #pragma unroll
    for (int u = 0; u < 4; ++u) {
      xb[u] = z2; gb[u] = z2;
      int jn = j + 4 + u;
      if (jn < m) {
        int s = ssrc[start + jn];
        xb[u] = *(const bf16x2*)(Xs + (long)s * 128 + c);
        if (isDis) gb[u] = *(const bf16x2*)(gate_s + (long)(start + jn) * 128 + c);
      }
    }

    float part[4], mm0[4], mm1[4];
    #pragma unroll
    for (int u = 0; u < 4; ++u) {
      float xs0 = (float)xa[u][0], xs1 = (float)xa[u][1];
      float m0 = xs0 + xd0, m1 = xs1 + xd1;
      if (isDis) { m0 *= (float)ga[u][0]; m1 *= (float)ga[u][1]; }
      mm0[u] = m0; mm1[u] = m1;
      part[u] = (xs0 * xd0 + xs1 * xd1) * 0.17677669529663687f
              + m0 * at[0] + m1 * at[1];
    }
    // 4 independent butterfly chains - pipeline in the DS unit
    #pragma unroll
    for (int dd = 1; dd <= 8; dd <<= 1) {
      #pragma unroll
      for (int u = 0; u < 4; ++u) part[u] += __shfl_xor(part[u], dd);
    }
    #pragma unroll
    for (int u = 0; u < 4; ++u) {
      float ex = (j + u < m) ? __expf(part[u]) : 0.f;
      n0 += mm0[u] * ex;
      n1 += mm1[u] * ex;
      den += ex;
    }
    #pragma unroll
    for (int u = 0; u < 4; ++u) { xa[u] = xb[u]; ga[u] = gb[u]; }
  }

  float r = __builtin_amdgcn_rcpf(den + 1e-16f);
  bf16x2 o;
  o[0] = (__bf16)(n0 * r);
  o[1] = (__bf16)(n1 * r);
  *(bf16x2*)(outp + (long)node * 128 + c) = o;
}

// ---------------------------------------------------------------------------
extern "C" void kernel_launch(void* const* d_in, const int* in_sizes, int n_in,
                              void* d_out, int out_size, void* d_ws, size_t ws_size,
                              hipStream_t stream)
{
  const float* x_drug  = (const float*)d_in[0];
  const float* x_dis   = (const float*)d_in[1];
  const float* ea      = (const float*)d_in[2];
  const int*   si_t    = (const int*)d_in[3];
  const int*   di_t    = (const int*)d_in[4];
  const int*   si_r    = (const int*)d_in[5];
  const int*   di_r    = (const int*)d_in[6];
  const float* Ws_t    = (const float*)d_in[7];
  const float* bs_t    = (const float*)d_in[8];
  const float* Wd_t    = (const float*)d_in[9];
  const float* bd_t    = (const float*)d_in[10];
  const float* attn_t  = (const float*)d_in[11];
  const float* Wg1     = (const float*)d_in[12];
  const float* bg1     = (const float*)d_in[13];
  const float* Wg2     = (const float*)d_in[14];
  const float* bg2     = (const float*)d_in[15];
  const float* Ws_r    = (const float*)d_in[16];
  const float* bs_r    = (const float*)d_in[17];
  const float* Wd_r    = (const float*)d_in[18];
  const float* bd_r    = (const float*)d_in[19];
  const float* attn_r  = (const float*)d_in[20];
  const float* Wo_drug = (const float*)d_in[21];
  const float* bo_drug = (const float*)d_in[22];
  const float* Wo_dis  = (const float*)d_in[23];
  const float* bo_dis  = (const float*)d_in[24];

  // workspace layout (~104 MB); X/gate tensors bf16.
  // aggr_dis aliases Xd_t, aggr_drug aliases Xd_r (row-for-row safe).
  __bf16* wsb      = (__bf16*)d_ws;
  __bf16* Xs_t     = wsb;                  // 50000*128
  __bf16* Xd_t     = Xs_t + 6400000;       // 20000*128 (-> aggr_dis)
  __bf16* Xs_r     = Xd_t + 2560000;       // 20000*128
  __bf16* Xd_r     = Xs_r + 2560000;       // 50000*128 (-> aggr_drug)
  __bf16* gate     = Xd_r + 6400000;       // NE_PAD*128, SORTED order
  int* cnt_dis    = (int*)(gate + (long)NE_PAD * 128);  // 20000  --+ contiguous:
  int* cnt_drug   = cnt_dis + 20000;       // 50000             | zeroed+scanned
  int* offs_dis   = cnt_drug + 50000;      // 20000             | as one region
  int* offs_drug  = offs_dis + 20000;      // 50000             |
  int* cur_dis    = offs_drug + 50000;     // 20000             |
  int* cur_drug   = cur_dis + 20000;       // 50000           --+
  int* sorted_t   = cur_drug + 50000;      // 250000 (gate kernel only)
  int* ssrc_t     = sorted_t + 250000;     // 250000
  int* ssrc_r     = ssrc_t + 250000;       // 250000
  int* bsum       = ssrc_r + 250000;       // 275
  int* bexc       = bsum + 512;            // 275

  __bf16* aggr_dis  = Xd_t;
  __bf16* aggr_drug = Xd_r;

  float* out_drug = (float*)d_out;
  float* out_dis  = out_drug + (long)N_DRUG * 128;

  hipMemsetAsync(cnt_dis, 0, 70000 * sizeof(int), stream);

  const int eb = (NE + 255) / 256;         // 977

  // counting sort by destination (both convs), device-wide 3-phase scan
  histo2<<<2 * eb, 256, 0, stream>>>(di_t, di_r, cnt_dis, cnt_drug, eb);
  scan_partial<<<NBT, 256, 0, stream>>>(cnt_dis, bsum);
  scan_block<<<1, 512, 0, stream>>>(bsum, bexc);
  scan_final<<<NBT, 256, 0, stream>>>(cnt_dis, bexc, offs_dis, cur_dis);
  scatter2<<<2 * eb, 256, 0, stream>>>(di_t, di_r, si_t, si_r, cur_dis, cur_drug,
                                       sorted_t, ssrc_t, ssrc_r, eb);

  // 4 node transforms, persistent per-segment blocks (tiles 782/313/313/782)
  Seg nd;
  nd.A[0] = x_drug; nd.W[0] = Ws_t; nd.bias[0] = bs_t; nd.out[0] = Xs_t; nd.M[0] = N_DRUG;
  nd.A[1] = x_dis;  nd.W[1] = Wd_t; nd.bias[1] = bd_t; nd.out[1] = Xd_t; nd.M[1] = N_DIS;
  nd.A[2] = x_dis;  nd.W[2] = Ws_r; nd.bias[2] = bs_r; nd.out[2] = Xs_r; nd.M[2] = N_DIS;
  nd.A[3] = x_drug; nd.W[3] = Wd_r; nd.bias[3] = bd_r; nd.out[3] = Xd_r; nd.M[3] = N_DRUG;
  nd.bstart[0] = 0; nd.bstart[1] = 274; nd.bstart[2] = 384; nd.bstart[3] = 494; nd.bstart[4] = 768;
  gemm_seg<0, 1><<<768, 256, 0, stream>>>(nd);

  // edge gate in sorted order, persistent blocks (2 blocks/CU, no tail)
  gate_kernel<<<512, 256, 0, stream>>>(ea, Wg2, Wg1, bg1, bg2, sorted_t, gate);

  // merged gather-side aggregation: 70000 waves, one per destination node
  aggregate2<<<(N_DIS + N_DRUG + 3) / 4, 256, 0, stream>>>(
      Xs_t, Xd_t, Xs_r, Xd_r, ssrc_t, ssrc_r, offs_dis, cnt_dis,
      gate, attn_t, attn_r, aggr_dis, aggr_drug);

  // 2 output linears, persistent per-segment blocks (tiles 782/313)
  Seg od;
  od.A[0] = aggr_drug; od.W[0] = Wo_drug; od.bias[0] = bo_drug; od.out[0] = out_drug; od.M[0] = N_DRUG;
  od.A[1] = aggr_dis;  od.W[1] = Wo_dis;  od.bias[1] = bo_dis;  od.out[1] = out_dis;  od.M[1] = N_DIS;
  od.A[2] = od.A[1];   od.W[2] = od.W[1]; od.bias[2] = od.bias[1]; od.out[2] = od.out[1]; od.M[2] = N_DIS;
  od.A[3] = od.A[1];   od.W[3] = od.W[1]; od.bias[3] = od.bias[1]; od.out[3] = od.out[1]; od.M[3] = N_DIS;
  od.bstart[0] = 0; od.bstart[1] = 548; od.bstart[2] = 768; od.bstart[3] = 768; od.bstart[4] = 768;
  gemm_seg<1, 0><<<768, 256, 0, stream>>>(od);
}